// Round 11
// baseline (313.637 us; speedup 1.0000x reference)
//
#include <hip/hip_runtime.h>
#include <hip/hip_bf16.h>
#include <math.h>

#define N_NODES 8192
#define IN_DIM  512
#define H_DIM   128
#define KC      1024              // K-chunk per k-block in k_A (bitmask path)
#define NKB     (N_NODES / KC)    // 8
#define BMR     64                // adj rows per k_A block (4 waves x 16)
#define NTW     (N_NODES / 64)    // bitmask u64 words per row (128)

typedef __attribute__((ext_vector_type(8))) short bf16x8;
typedef __attribute__((ext_vector_type(4))) float f32x4;

__device__ __forceinline__ float lrelu(float x) { return fmaxf(x, 0.2f * x); }

__device__ __forceinline__ unsigned int f2mono(float x) {
    unsigned int b = __float_as_uint(x);
    return (b & 0x80000000u) ? ~b : (b | 0x80000000u);
}
__device__ __forceinline__ float mono2f(unsigned int u) {
    unsigned int b = (u & 0x80000000u) ? (u ^ 0x80000000u) : ~u;
    return __uint_as_float(b);
}

__device__ __forceinline__ short f2bf(float x) {
    union { __hip_bfloat16 h; short s; } cv;
    cv.h = __float2bfloat16(x);
    return cv.s;
}

// Zero-fill (replaces hipMemsetAsync: the runtime's fillBufferAligned ran at
// 27 GB/s and was the TOP dispatch at ~156us -- round-10 post-mortem).
__global__ __launch_bounds__(256) void k_zero(f32x4* __restrict__ p, int n16) {
    int i = blockIdx.x * 256 + threadIdx.x;
    if (i < n16) {
        f32x4 zv = {0.f, 0.f, 0.f, 0.f};
        __builtin_nontemporal_store(zv, p + i);
    }
}

// Wh = h @ W_w^T + W_b (f32) ; also WhT = bf16 transpose [H_DIM][N_NODES]
__global__ __launch_bounds__(256) void k_wh(const float* __restrict__ h,
                                            const float* __restrict__ Ww,
                                            const float* __restrict__ Wb,
                                            float* __restrict__ Wh,
                                            __hip_bfloat16* __restrict__ WhT) {
    const int BM = 32, BK = 64;
    __shared__ float hT[BK][BM + 4];
    __shared__ float wT[BK][H_DIM + 4];
    const int tid = threadIdx.x;
    const int w = tid >> 6, lane = tid & 63;
    const int trm = tid >> 5, tcm = tid & 31;
    const int row0 = blockIdx.x * BM;

    float acc[4][4] = {};
    for (int k0 = 0; k0 < IN_DIM; k0 += BK) {
        __syncthreads();
        #pragma unroll
        for (int p = 0; p < 8; ++p) {
            int r = 4 * p + w;
            hT[lane][r] = h[(size_t)(row0 + r) * IN_DIM + k0 + lane];
        }
        #pragma unroll
        for (int p = 0; p < 32; ++p) {
            int c = 4 * p + w;
            wT[lane][c] = Ww[(size_t)c * IN_DIM + k0 + lane];
        }
        __syncthreads();
        #pragma unroll 8
        for (int kk = 0; kk < BK; ++kk) {
            f32x4 a4 = *(const f32x4*)&hT[kk][4 * trm];
            f32x4 b4 = *(const f32x4*)&wT[kk][4 * tcm];
            #pragma unroll
            for (int i = 0; i < 4; ++i)
                #pragma unroll
                for (int j = 0; j < 4; ++j)
                    acc[i][j] = fmaf(a4[i], b4[j], acc[i][j]);
        }
    }
    f32x4 wb4 = *(const f32x4*)&Wb[4 * tcm];
    #pragma unroll
    for (int i = 0; i < 4; ++i) {
        int row = row0 + 4 * trm + i;
        f32x4 v;
        #pragma unroll
        for (int jj = 0; jj < 4; ++jj) v[jj] = acc[i][jj] + wb4[jj];
        *(f32x4*)&Wh[(size_t)row * H_DIM + 4 * tcm] = v;
        #pragma unroll
        for (int jj = 0; jj < 4; ++jj)
            WhT[(size_t)(4 * tcm + jj) * N_NODES + row] = __float2bfloat16(v[jj]);
    }
}

// s_i = Wh_i . a ; global max(s) via mapped atomicMax
__global__ __launch_bounds__(256) void k_s(const float* __restrict__ Wh,
                                           const float* __restrict__ a,
                                           float* __restrict__ s,
                                           unsigned int* __restrict__ smax) {
    const int w = threadIdx.x >> 6, lane = threadIdx.x & 63;
    const int row = blockIdx.x * 4 + w;
    float2 av = *(const float2*)&a[lane * 2];
    float2 wh = *(const float2*)&Wh[(size_t)row * H_DIM + lane * 2];
    float v = wh.x * av.x + wh.y * av.y;
    #pragma unroll
    for (int off = 32; off > 0; off >>= 1) v += __shfl_down(v, off);
    __shared__ float bmax[4];
    if (lane == 0) { s[row] = v; bmax[w] = v; }
    __syncthreads();
    if (threadIdx.x == 0) {
        float m = fmaxf(fmaxf(bmax[0], bmax[1]), fmaxf(bmax[2], bmax[3]));
        atomicMax(smax, f2mono(m));
    }
}

// Streaming compress: bmask[row] bit j = (adj[row][j] != 0). One wave per row,
// 1KB contiguous nontemporal reads per wave-instr; nibbles packed to u64 via
// 4x shfl_xor OR-reduce; lanes 0/16/32/48 write the 4 words.
__global__ __launch_bounds__(256) void k_mask(const float* __restrict__ adj,
                                              unsigned long long* __restrict__ bm) {
    const int lane = threadIdx.x & 63;
    const int row  = blockIdx.x * 4 + (threadIdx.x >> 6);
    const float* arow = adj + (size_t)row * N_NODES;
    unsigned long long* mrow = bm + (size_t)row * NTW;
    #pragma unroll 4
    for (int c = 0; c < N_NODES / 256; ++c) {      // 32 chunks of 256 cols
        f32x4 a4 = __builtin_nontemporal_load((const f32x4*)(arow + c * 256 + lane * 4));
        unsigned long long v = 0ull;
        v |= (a4[0] != 0.f) ? 1ull : 0ull;
        v |= (a4[1] != 0.f) ? 2ull : 0ull;
        v |= (a4[2] != 0.f) ? 4ull : 0ull;
        v |= (a4[3] != 0.f) ? 8ull : 0ull;
        v <<= (4 * (lane & 15));
        v |= __shfl_xor(v, 1);
        v |= __shfl_xor(v, 2);
        v |= __shfl_xor(v, 4);
        v |= __shfl_xor(v, 8);
        if ((lane & 15) == 0)
            mrow[c * 4 + (lane >> 4)] = v;
    }
}

// MFMA pass driven by the 8MB bitmask instead of the 268MB adj: NO LDS, NO
// barriers, no vmcnt drains. Each wave owns 16 rows x all 128 H cols; per 64
// cols it reads one u64 mask word (broadcast across kq lanes), computes exp
// once per (i,j), and runs 16 MFMAs.
__global__ __launch_bounds__(256) void k_A(const unsigned long long* __restrict__ bm,
                                           const __hip_bfloat16* __restrict__ WhT,
                                           const float* __restrict__ s,
                                           const unsigned int* __restrict__ smaxp,
                                           float* __restrict__ denom,
                                           float* __restrict__ y) {
    const int lane = threadIdx.x & 63;
    const int w    = threadIdx.x >> 6;   // wave = row-group of 16
    const int r16  = lane & 15;
    const int kq   = lane >> 4;          // k-quarter: k = kq*8 + e
    const int row0 = blockIdx.x * BMR;
    const int j0   = blockIdx.y * KC;
    const int rowA = row0 + w * 16 + r16;

    const float smax = mono2f(*smaxp);
    const float si = s[rowA];
    const float mi = lrelu(si + smax);

    f32x4 acc[8] = {{0.f,0.f,0.f,0.f},{0.f,0.f,0.f,0.f},{0.f,0.f,0.f,0.f},{0.f,0.f,0.f,0.f},
                    {0.f,0.f,0.f,0.f},{0.f,0.f,0.f,0.f},{0.f,0.f,0.f,0.f},{0.f,0.f,0.f,0.f}};
    float dsum = 0.f;

    const float* sp = s + j0 + kq * 8;
    const __hip_bfloat16* bp = WhT + (size_t)r16 * N_NODES + j0 + kq * 8;
    const unsigned long long* mrow = bm + (size_t)rowA * NTW + (j0 >> 6);

    for (int bs = 0; bs < KC / 64; ++bs) {         // 16 mask words
        unsigned long long m64 = mrow[bs];
        #pragma unroll
        for (int sub = 0; sub < 2; ++sub) {
            const int ts = bs * 2 + sub;           // 32-col step in [0, KC/32)
            unsigned int bits = (unsigned int)(m64 >> (sub * 32 + kq * 8)) & 0xffu;

            f32x4 sc0 = *(const f32x4*)(sp + ts * 32);
            f32x4 sc1 = *(const f32x4*)(sp + ts * 32 + 4);
            float sv[8] = {sc0[0], sc0[1], sc0[2], sc0[3], sc1[0], sc1[1], sc1[2], sc1[3]};
            bf16x8 afrag;
            #pragma unroll
            for (int e = 0; e < 8; ++e) {
                bool nb = (bits >> e) & 1u;
                float ex = nb ? __expf(lrelu(si + sv[e]) - mi) : 0.f;
                dsum += ex;
                afrag[e] = f2bf(ex);
            }
            #pragma unroll
            for (int half = 0; half < 2; ++half) {
                bf16x8 bc[4];
                #pragma unroll
                for (int f = 0; f < 4; ++f)
                    bc[f] = *(const bf16x8*)(bp + (size_t)ts * 32 +
                                             (size_t)(half * 4 + f) * 16 * N_NODES);
                #pragma unroll
                for (int f = 0; f < 4; ++f)
                    acc[half * 4 + f] =
                        __builtin_amdgcn_mfma_f32_16x16x32_bf16(afrag, bc[f], acc[half * 4 + f], 0, 0, 0);
            }
        }
    }

    // denom partial: reduce over kq lanes (same r16)
    {
        float v = dsum;
        v += __shfl_xor(v, 16);
        v += __shfl_xor(v, 32);
        if (lane < 16) atomicAdd(&denom[row0 + w * 16 + lane], v);
    }
    // y partial: D layout col = f*16 + (lane&15), row = (lane>>4)*4 + reg
    #pragma unroll
    for (int f = 0; f < 8; ++f)
        #pragma unroll
        for (int i = 0; i < 4; ++i) {
            int rr = row0 + w * 16 + kq * 4 + i;
            int cc = f * 16 + r16;
            atomicAdd(&y[(size_t)rr * H_DIM + cc], acc[f][i]);
        }
}

// Fallback (ws too small for bmask): round-9 staged kernel, adj-direct.
__global__ __launch_bounds__(256) void k_A_fb(const float* __restrict__ adj,
                                              const __hip_bfloat16* __restrict__ WhT,
                                              const float* __restrict__ s,
                                              const unsigned int* __restrict__ smaxp,
                                              float* __restrict__ denom,
                                              float* __restrict__ y) {
    __shared__ unsigned char msk[BMR * 64];
    const int tid  = threadIdx.x;
    const int lane = tid & 63;
    const int w    = tid >> 6;
    const int r16  = lane & 15;
    const int kq   = lane >> 4;
    const int row0 = blockIdx.x * BMR;
    const int j0base = blockIdx.y * KC;
    const int rowA = row0 + w * 16 + r16;

    const float smax = mono2f(*smaxp);
    const float si = s[rowA];
    const float mi = lrelu(si + smax);

    f32x4 acc[8] = {{0.f,0.f,0.f,0.f},{0.f,0.f,0.f,0.f},{0.f,0.f,0.f,0.f},{0.f,0.f,0.f,0.f},
                    {0.f,0.f,0.f,0.f},{0.f,0.f,0.f,0.f},{0.f,0.f,0.f,0.f},{0.f,0.f,0.f,0.f}};
    float dsum = 0.f;

    const float* sp = s + j0base + kq * 8;
    const __hip_bfloat16* bp = WhT + (size_t)r16 * N_NODES + j0base + kq * 8;

    int sRow[4], sCol[4];
    #pragma unroll
    for (int p = 0; p < 4; ++p) {
        int seg = p * 256 + tid;
        sRow[p] = seg >> 4;
        sCol[p] = (seg & 15) * 4;
    }
    const int NBIG = KC / 64;
    f32x4 areg[4];
    #pragma unroll
    for (int p = 0; p < 4; ++p)
        areg[p] = __builtin_nontemporal_load(
            (const f32x4*)(adj + (size_t)(row0 + sRow[p]) * N_NODES + j0base + sCol[p]));

    for (int bs = 0; bs < NBIG; ++bs) {
        __syncthreads();
        #pragma unroll
        for (int p = 0; p < 4; ++p) {
            f32x4 a4 = areg[p];
            unsigned int mwd = 0u;
            mwd |= (a4[0] != 0.f) ? 0x00000001u : 0u;
            mwd |= (a4[1] != 0.f) ? 0x00000100u : 0u;
            mwd |= (a4[2] != 0.f) ? 0x00010000u : 0u;
            mwd |= (a4[3] != 0.f) ? 0x01000000u : 0u;
            int r = sRow[p], c = sCol[p];
            int slot = (c >> 3) ^ (r & 7);
            *(unsigned int*)&msk[r * 64 + (slot << 3) + (c & 7)] = mwd;
        }
        __syncthreads();
        if (bs + 1 < NBIG) {
            const int j1 = j0base + (bs + 1) * 64;
            #pragma unroll
            for (int p = 0; p < 4; ++p)
                areg[p] = __builtin_nontemporal_load(
                    (const f32x4*)(adj + (size_t)(row0 + sRow[p]) * N_NODES + j1 + sCol[p]));
        }
        #pragma unroll
        for (int sub = 0; sub < 2; ++sub) {
            const int ts = bs * 2 + sub;
            const int rT = w * 16 + r16;
            const int slotR = (sub * 4 + kq) ^ (r16 & 7);
            unsigned long long m8 = *(const unsigned long long*)&msk[rT * 64 + (slotR << 3)];
            unsigned int bits = (unsigned int)((m8 * 0x0102040810204080ull) >> 56) & 0xffu;

            f32x4 sc0 = *(const f32x4*)(sp + ts * 32);
            f32x4 sc1 = *(const f32x4*)(sp + ts * 32 + 4);
            float sv[8] = {sc0[0], sc0[1], sc0[2], sc0[3], sc1[0], sc1[1], sc1[2], sc1[3]};
            bf16x8 afrag;
            #pragma unroll
            for (int e = 0; e < 8; ++e) {
                bool nb = (bits >> e) & 1u;
                float ex = nb ? __expf(lrelu(si + sv[e]) - mi) : 0.f;
                dsum += ex;
                afrag[e] = f2bf(ex);
            }
            #pragma unroll
            for (int half = 0; half < 2; ++half) {
                bf16x8 bc[4];
                #pragma unroll
                for (int f = 0; f < 4; ++f)
                    bc[f] = *(const bf16x8*)(bp + (size_t)ts * 32 +
                                             (size_t)(half * 4 + f) * 16 * N_NODES);
                #pragma unroll
                for (int f = 0; f < 4; ++f)
                    acc[half * 4 + f] =
                        __builtin_amdgcn_mfma_f32_16x16x32_bf16(afrag, bc[f], acc[half * 4 + f], 0, 0, 0);
            }
        }
    }
    {
        float v = dsum;
        v += __shfl_xor(v, 16);
        v += __shfl_xor(v, 32);
        if (lane < 16) atomicAdd(&denom[row0 + w * 16 + lane], v);
    }
    #pragma unroll
    for (int f = 0; f < 8; ++f)
        #pragma unroll
        for (int i = 0; i < 4; ++i) {
            int rr = row0 + w * 16 + kq * 4 + i;
            int cc = f * 16 + r16;
            atomicAdd(&y[(size_t)rr * H_DIM + cc], acc[f][i]);
        }
}

// alpha_ij = ex_ij / denom_i ; reads 8MB bitmask (or adj fallback), writes 268MB nt
__global__ __launch_bounds__(256) void k_B(const unsigned long long* __restrict__ bmask,
                                           const float* __restrict__ adj,
                                           const float* __restrict__ s,
                                           const float* __restrict__ denom,
                                           const unsigned int* __restrict__ smaxp,
                                           float* __restrict__ alpha,
                                           int use_mask) {
    const int NSTEP = N_NODES / 256;
    const int w = threadIdx.x >> 6, lane = threadIdx.x & 63;
    const int row = blockIdx.x * 4 + w;
    const float smax = mono2f(*smaxp);
    const float si = s[row];
    const float mi = lrelu(si + smax);
    const float d = denom[row];
    const float rd = d > 0.f ? 1.f / d : 0.f;
    float* arow = alpha + (size_t)row * N_NODES;
    if (use_mask) {
        const unsigned long long* mrow = bmask + (size_t)row * NTW;
        #pragma unroll 4
        for (int t = 0; t < NSTEP; ++t) {
            int col = t * 256 + lane * 4;
            unsigned long long mb = mrow[t * 4 + (lane >> 4)];
            int sh = (lane & 15) * 4;
            f32x4 sj = *(const f32x4*)&s[col];
            f32x4 o;
            o[0] = ((mb >> (sh + 0)) & 1ull) ? __expf(lrelu(si + sj[0]) - mi) * rd : 0.f;
            o[1] = ((mb >> (sh + 1)) & 1ull) ? __expf(lrelu(si + sj[1]) - mi) * rd : 0.f;
            o[2] = ((mb >> (sh + 2)) & 1ull) ? __expf(lrelu(si + sj[2]) - mi) * rd : 0.f;
            o[3] = ((mb >> (sh + 3)) & 1ull) ? __expf(lrelu(si + sj[3]) - mi) * rd : 0.f;
            __builtin_nontemporal_store(o, (f32x4*)&arow[col]);
        }
    } else {
        const float* adjrow = adj + (size_t)row * N_NODES;
        #pragma unroll 4
        for (int t = 0; t < NSTEP; ++t) {
            int col = t * 256 + lane * 4;
            f32x4 a4 = __builtin_nontemporal_load((const f32x4*)&adjrow[col]);
            f32x4 sj = *(const f32x4*)&s[col];
            f32x4 o;
            o[0] = (a4[0] != 0.f) ? __expf(lrelu(si + sj[0]) - mi) * rd : 0.f;
            o[1] = (a4[1] != 0.f) ? __expf(lrelu(si + sj[1]) - mi) * rd : 0.f;
            o[2] = (a4[2] != 0.f) ? __expf(lrelu(si + sj[2]) - mi) * rd : 0.f;
            o[3] = (a4[3] != 0.f) ? __expf(lrelu(si + sj[3]) - mi) * rd : 0.f;
            __builtin_nontemporal_store(o, (f32x4*)&arow[col]);
        }
    }
}

// z = sigmoid(y/denom)
__global__ __launch_bounds__(256) void k_z(const float* __restrict__ y,
                                           const float* __restrict__ denom,
                                           float* __restrict__ z) {
    int i = blockIdx.x * 256 + threadIdx.x;
    int row = i >> 7;
    float d = denom[row];
    float rd = d > 0.f ? 1.f / d : 0.f;
    float v = y[i] * rd;
    z[i] = 1.f / (1.f + __expf(-v));
}

extern "C" void kernel_launch(void* const* d_in, const int* in_sizes, int n_in,
                              void* d_out, int out_size, void* d_ws, size_t ws_size,
                              hipStream_t stream) {
    const float* h   = (const float*)d_in[0];
    const float* adj = (const float*)d_in[1];
    const float* Ww  = (const float*)d_in[2];
    const float* Wb  = (const float*)d_in[3];
    const float* a   = (const float*)d_in[4];

    float* z     = (float*)d_out;
    float* alpha = z + (size_t)N_NODES * H_DIM;

    char* ws = (char*)d_ws;
    float* y     = (float*)ws;  ws += sizeof(float) * (size_t)N_NODES * H_DIM;   // 4MB (zeroed)
    float* denom = (float*)ws;  ws += sizeof(float) * N_NODES;                   // 32KB (zeroed)
    unsigned int* smax = (unsigned int*)ws;  ws += 256;                          // (zeroed)
    size_t zero_bytes = (size_t)(ws - (char*)d_ws);
    float* Wh    = (float*)ws;  ws += sizeof(float) * (size_t)N_NODES * H_DIM;   // 4MB
    __hip_bfloat16* WhT = (__hip_bfloat16*)ws;
    ws += sizeof(__hip_bfloat16) * (size_t)N_NODES * H_DIM;                      // 2MB
    float* s     = (float*)ws;  ws += sizeof(float) * N_NODES;                   // 32KB
    unsigned long long* bmask = (unsigned long long*)ws;
    size_t base_need  = (size_t)(ws - (char*)d_ws);
    size_t mask_bytes = (size_t)N_NODES * NTW * sizeof(unsigned long long);      // 8MB
    int use_mask = (ws_size >= base_need + mask_bytes) ? 1 : 0;

    // custom zero kernel: hipMemsetAsync's fillBufferAligned ran at 27 GB/s
    // (156us, the top dispatch in round 10)
    int n16 = (int)(zero_bytes / 16);
    hipLaunchKernelGGL(k_zero, dim3((n16 + 255) / 256), dim3(256), 0, stream,
                       (f32x4*)d_ws, n16);
    if (use_mask)
        hipLaunchKernelGGL(k_mask, dim3(N_NODES / 4), dim3(256), 0, stream, adj, bmask);
    hipLaunchKernelGGL(k_wh, dim3(N_NODES / 32), dim3(256), 0, stream, h, Ww, Wb, Wh, WhT);
    hipLaunchKernelGGL(k_s,  dim3(N_NODES / 4),  dim3(256), 0, stream, Wh, a, s, smax);
    if (use_mask)
        hipLaunchKernelGGL(k_A, dim3(N_NODES / BMR, NKB), dim3(256), 0, stream,
                           bmask, WhT, s, smax, denom, y);
    else
        hipLaunchKernelGGL(k_A_fb, dim3(N_NODES / BMR, NKB), dim3(256), 0, stream,
                           adj, WhT, s, smax, denom, y);
    hipLaunchKernelGGL(k_B,  dim3(N_NODES / 4),  dim3(256), 0, stream,
                       bmask, adj, s, denom, smax, alpha, use_mask);
    hipLaunchKernelGGL(k_z,  dim3((N_NODES * H_DIM) / 256), dim3(256), 0, stream,
                       y, denom, z);
}

// Round 12
// 252.373 us; speedup vs baseline: 1.2427x; 1.2427x over previous
//
#include <hip/hip_runtime.h>
#include <hip/hip_bf16.h>
#include <math.h>

#define N_NODES 8192
#define IN_DIM  512
#define H_DIM   128
#define KC      1024              // K-chunk per k-block in k_A (bitmask path)
#define NKB     (N_NODES / KC)    // 8
#define BMR     64                // adj rows per k_A block (4 waves x 16)
#define NTW     (N_NODES / 64)    // bitmask u64 words per row (128)

typedef __attribute__((ext_vector_type(8))) short bf16x8;
typedef __attribute__((ext_vector_type(4))) float f32x4;

__device__ __forceinline__ float lrelu(float x) { return fmaxf(x, 0.2f * x); }

__device__ __forceinline__ unsigned int f2mono(float x) {
    unsigned int b = __float_as_uint(x);
    return (b & 0x80000000u) ? ~b : (b | 0x80000000u);
}
__device__ __forceinline__ float mono2f(unsigned int u) {
    unsigned int b = (u & 0x80000000u) ? (u ^ 0x80000000u) : ~u;
    return __uint_as_float(b);
}

__device__ __forceinline__ short f2bf(float x) {
    union { __hip_bfloat16 h; short s; } cv;
    cv.h = __float2bfloat16(x);
    return cv.s;
}

// Zero-fill (hipMemsetAsync's fillBufferAligned ran at 27 GB/s in round 10)
__global__ __launch_bounds__(256) void k_zero(f32x4* __restrict__ p, int n16) {
    int i = blockIdx.x * 256 + threadIdx.x;
    if (i < n16) {
        f32x4 zv = {0.f, 0.f, 0.f, 0.f};
        __builtin_nontemporal_store(zv, p + i);
    }
}

// Wh = h @ W_w^T + W_b (f32) ; also WhT2 = bf16 FRAGMENT-SWIZZLED transpose.
// Round-12: k_A's B-fragment loads from row-major WhT[H][N] were 16 scattered
// 64B segments (16KB stride) per instruction -- the round-6 pathology moved to
// L2. WhT2[ts][f][lane][e] stores fragments in consume order so each k_A
// bc[f] load is one wave-contiguous 1KB burst.
//   element (node j, hcol c): ts=j>>5, kq=(j>>3)&3, e=j&7, f=c>>4, r16=c&15
//   WhT2[ ((ts*8+f)*64 + kq*16+r16)*8 + e ]
__global__ __launch_bounds__(256) void k_wh(const float* __restrict__ h,
                                            const float* __restrict__ Ww,
                                            const float* __restrict__ Wb,
                                            float* __restrict__ Wh,
                                            __hip_bfloat16* __restrict__ WhT2) {
    const int BM = 32, BK = 64;
    __shared__ float hT[BK][BM + 4];
    __shared__ float wT[BK][H_DIM + 4];
    const int tid = threadIdx.x;
    const int w = tid >> 6, lane = tid & 63;
    const int trm = tid >> 5, tcm = tid & 31;
    const int row0 = blockIdx.x * BM;

    float acc[4][4] = {};
    for (int k0 = 0; k0 < IN_DIM; k0 += BK) {
        __syncthreads();
        #pragma unroll
        for (int p = 0; p < 8; ++p) {
            int r = 4 * p + w;
            hT[lane][r] = h[(size_t)(row0 + r) * IN_DIM + k0 + lane];
        }
        #pragma unroll
        for (int p = 0; p < 32; ++p) {
            int c = 4 * p + w;
            wT[lane][c] = Ww[(size_t)c * IN_DIM + k0 + lane];
        }
        __syncthreads();
        #pragma unroll 8
        for (int kk = 0; kk < BK; ++kk) {
            f32x4 a4 = *(const f32x4*)&hT[kk][4 * trm];
            f32x4 b4 = *(const f32x4*)&wT[kk][4 * tcm];
            #pragma unroll
            for (int i = 0; i < 4; ++i)
                #pragma unroll
                for (int j = 0; j < 4; ++j)
                    acc[i][j] = fmaf(a4[i], b4[j], acc[i][j]);
        }
    }
    f32x4 wb4 = *(const f32x4*)&Wb[4 * tcm];
    #pragma unroll
    for (int i = 0; i < 4; ++i) {
        int row = row0 + 4 * trm + i;          // node j
        f32x4 v;
        #pragma unroll
        for (int jj = 0; jj < 4; ++jj) v[jj] = acc[i][jj] + wb4[jj];
        *(f32x4*)&Wh[(size_t)row * H_DIM + 4 * tcm] = v;
        int ts = row >> 5, kq = (row >> 3) & 3, e = row & 7;
        #pragma unroll
        for (int jj = 0; jj < 4; ++jj) {
            int c = 4 * tcm + jj;
            int f = c >> 4, r16 = c & 15;
            WhT2[((size_t)(ts * 8 + f) * 64 + kq * 16 + r16) * 8 + e] =
                __float2bfloat16(v[jj]);
        }
    }
}

// s_i = Wh_i . a ; global max(s) via mapped atomicMax
__global__ __launch_bounds__(256) void k_s(const float* __restrict__ Wh,
                                           const float* __restrict__ a,
                                           float* __restrict__ s,
                                           unsigned int* __restrict__ smax) {
    const int w = threadIdx.x >> 6, lane = threadIdx.x & 63;
    const int row = blockIdx.x * 4 + w;
    float2 av = *(const float2*)&a[lane * 2];
    float2 wh = *(const float2*)&Wh[(size_t)row * H_DIM + lane * 2];
    float v = wh.x * av.x + wh.y * av.y;
    #pragma unroll
    for (int off = 32; off > 0; off >>= 1) v += __shfl_down(v, off);
    __shared__ float bmax[4];
    if (lane == 0) { s[row] = v; bmax[w] = v; }
    __syncthreads();
    if (threadIdx.x == 0) {
        float m = fmaxf(fmaxf(bmax[0], bmax[1]), fmaxf(bmax[2], bmax[3]));
        atomicMax(smax, f2mono(m));
    }
}

// Streaming compress: bmask[row] bit j = (adj[row][j] != 0).
__global__ __launch_bounds__(256) void k_mask(const float* __restrict__ adj,
                                              unsigned long long* __restrict__ bm) {
    const int lane = threadIdx.x & 63;
    const int row  = blockIdx.x * 4 + (threadIdx.x >> 6);
    const float* arow = adj + (size_t)row * N_NODES;
    unsigned long long* mrow = bm + (size_t)row * NTW;
    #pragma unroll 4
    for (int c = 0; c < N_NODES / 256; ++c) {      // 32 chunks of 256 cols
        f32x4 a4 = __builtin_nontemporal_load((const f32x4*)(arow + c * 256 + lane * 4));
        unsigned long long v = 0ull;
        v |= (a4[0] != 0.f) ? 1ull : 0ull;
        v |= (a4[1] != 0.f) ? 2ull : 0ull;
        v |= (a4[2] != 0.f) ? 4ull : 0ull;
        v |= (a4[3] != 0.f) ? 8ull : 0ull;
        v <<= (4 * (lane & 15));
        v |= __shfl_xor(v, 1);
        v |= __shfl_xor(v, 2);
        v |= __shfl_xor(v, 4);
        v |= __shfl_xor(v, 8);
        if ((lane & 15) == 0)
            mrow[c * 4 + (lane >> 4)] = v;
    }
}

// MFMA pass driven by the 8MB bitmask. NO LDS, NO barriers. Each wave owns 16
// rows x all 128 H cols. B-fragments now load from the swizzled WhT2: one
// contiguous 1KB wave-burst per fragment.
__global__ __launch_bounds__(256) void k_A(const unsigned long long* __restrict__ bm,
                                           const __hip_bfloat16* __restrict__ WhT2,
                                           const float* __restrict__ s,
                                           const unsigned int* __restrict__ smaxp,
                                           float* __restrict__ denom,
                                           float* __restrict__ y) {
    const int lane = threadIdx.x & 63;
    const int w    = threadIdx.x >> 6;   // wave = row-group of 16
    const int r16  = lane & 15;
    const int kq   = lane >> 4;          // k-quarter: k = kq*8 + e
    const int row0 = blockIdx.x * BMR;
    const int j0   = blockIdx.y * KC;
    const int rowA = row0 + w * 16 + r16;

    const float smax = mono2f(*smaxp);
    const float si = s[rowA];
    const float mi = lrelu(si + smax);

    f32x4 acc[8] = {{0.f,0.f,0.f,0.f},{0.f,0.f,0.f,0.f},{0.f,0.f,0.f,0.f},{0.f,0.f,0.f,0.f},
                    {0.f,0.f,0.f,0.f},{0.f,0.f,0.f,0.f},{0.f,0.f,0.f,0.f},{0.f,0.f,0.f,0.f}};
    float dsum = 0.f;

    const float* sp = s + j0 + kq * 8;
    const unsigned long long* mrow = bm + (size_t)rowA * NTW + (j0 >> 6);

    for (int bs = 0; bs < KC / 64; ++bs) {         // 16 mask words
        unsigned long long m64 = mrow[bs];
        #pragma unroll
        for (int sub = 0; sub < 2; ++sub) {
            const int ts = bs * 2 + sub;           // 32-col step in [0, KC/32)
            unsigned int bits = (unsigned int)(m64 >> (sub * 32 + kq * 8)) & 0xffu;

            f32x4 sc0 = *(const f32x4*)(sp + ts * 32);
            f32x4 sc1 = *(const f32x4*)(sp + ts * 32 + 4);
            float sv[8] = {sc0[0], sc0[1], sc0[2], sc0[3], sc1[0], sc1[1], sc1[2], sc1[3]};
            bf16x8 afrag;
            #pragma unroll
            for (int e = 0; e < 8; ++e) {
                bool nb = (bits >> e) & 1u;
                float ex = nb ? __expf(lrelu(si + sv[e]) - mi) : 0.f;
                dsum += ex;
                afrag[e] = f2bf(ex);
            }
            // swizzled fragment base: one 1KB contiguous burst per f
            const __hip_bfloat16* base =
                WhT2 + (size_t)((j0 >> 5) + ts) * 4096 + lane * 8;
            #pragma unroll
            for (int half = 0; half < 2; ++half) {
                bf16x8 bc[4];
                #pragma unroll
                for (int f = 0; f < 4; ++f)
                    bc[f] = *(const bf16x8*)(base + (half * 4 + f) * 512);
                #pragma unroll
                for (int f = 0; f < 4; ++f)
                    acc[half * 4 + f] =
                        __builtin_amdgcn_mfma_f32_16x16x32_bf16(afrag, bc[f], acc[half * 4 + f], 0, 0, 0);
            }
        }
    }

    // denom partial: reduce over kq lanes (same r16)
    {
        float v = dsum;
        v += __shfl_xor(v, 16);
        v += __shfl_xor(v, 32);
        if (lane < 16) atomicAdd(&denom[row0 + w * 16 + lane], v);
    }
    // y partial: D layout col = f*16 + (lane&15), row = (lane>>4)*4 + reg
    #pragma unroll
    for (int f = 0; f < 8; ++f)
        #pragma unroll
        for (int i = 0; i < 4; ++i) {
            int rr = row0 + w * 16 + kq * 4 + i;
            int cc = f * 16 + r16;
            atomicAdd(&y[(size_t)rr * H_DIM + cc], acc[f][i]);
        }
}

// Fallback (ws too small for bmask): staged adj-direct, swizzled WhT2 consume.
__global__ __launch_bounds__(256) void k_A_fb(const float* __restrict__ adj,
                                              const __hip_bfloat16* __restrict__ WhT2,
                                              const float* __restrict__ s,
                                              const unsigned int* __restrict__ smaxp,
                                              float* __restrict__ denom,
                                              float* __restrict__ y) {
    __shared__ unsigned char msk[BMR * 64];
    const int tid  = threadIdx.x;
    const int lane = tid & 63;
    const int w    = tid >> 6;
    const int r16  = lane & 15;
    const int kq   = lane >> 4;
    const int row0 = blockIdx.x * BMR;
    const int j0base = blockIdx.y * KC;
    const int rowA = row0 + w * 16 + r16;

    const float smax = mono2f(*smaxp);
    const float si = s[rowA];
    const float mi = lrelu(si + smax);

    f32x4 acc[8] = {{0.f,0.f,0.f,0.f},{0.f,0.f,0.f,0.f},{0.f,0.f,0.f,0.f},{0.f,0.f,0.f,0.f},
                    {0.f,0.f,0.f,0.f},{0.f,0.f,0.f,0.f},{0.f,0.f,0.f,0.f},{0.f,0.f,0.f,0.f}};
    float dsum = 0.f;

    const float* sp = s + j0base + kq * 8;

    int sRow[4], sCol[4];
    #pragma unroll
    for (int p = 0; p < 4; ++p) {
        int seg = p * 256 + tid;
        sRow[p] = seg >> 4;
        sCol[p] = (seg & 15) * 4;
    }
    const int NBIG = KC / 64;
    f32x4 areg[4];
    #pragma unroll
    for (int p = 0; p < 4; ++p)
        areg[p] = __builtin_nontemporal_load(
            (const f32x4*)(adj + (size_t)(row0 + sRow[p]) * N_NODES + j0base + sCol[p]));

    for (int bs = 0; bs < NBIG; ++bs) {
        __syncthreads();
        #pragma unroll
        for (int p = 0; p < 4; ++p) {
            f32x4 a4 = areg[p];
            unsigned int mwd = 0u;
            mwd |= (a4[0] != 0.f) ? 0x00000001u : 0u;
            mwd |= (a4[1] != 0.f) ? 0x00000100u : 0u;
            mwd |= (a4[2] != 0.f) ? 0x00010000u : 0u;
            mwd |= (a4[3] != 0.f) ? 0x01000000u : 0u;
            int r = sRow[p], c = sCol[p];
            int slot = (c >> 3) ^ (r & 7);
            *(unsigned int*)&msk[r * 64 + (slot << 3) + (c & 7)] = mwd;
        }
        __syncthreads();
        if (bs + 1 < NBIG) {
            const int j1 = j0base + (bs + 1) * 64;
            #pragma unroll
            for (int p = 0; p < 4; ++p)
                areg[p] = __builtin_nontemporal_load(
                    (const f32x4*)(adj + (size_t)(row0 + sRow[p]) * N_NODES + j1 + sCol[p]));
        }
        #pragma unroll
        for (int sub = 0; sub < 2; ++sub) {
            const int ts = bs * 2 + sub;
            const int rT = w * 16 + r16;
            const int slotR = (sub * 4 + kq) ^ (r16 & 7);
            unsigned long long m8 = *(const unsigned long long*)&msk[rT * 64 + (slotR << 3)];
            unsigned int bits = (unsigned int)((m8 * 0x0102040810204080ull) >> 56) & 0xffu;

            f32x4 sc0 = *(const f32x4*)(sp + ts * 32);
            f32x4 sc1 = *(const f32x4*)(sp + ts * 32 + 4);
            float sv[8] = {sc0[0], sc0[1], sc0[2], sc0[3], sc1[0], sc1[1], sc1[2], sc1[3]};
            bf16x8 afrag;
            #pragma unroll
            for (int e = 0; e < 8; ++e) {
                bool nb = (bits >> e) & 1u;
                float ex = nb ? __expf(lrelu(si + sv[e]) - mi) : 0.f;
                dsum += ex;
                afrag[e] = f2bf(ex);
            }
            const __hip_bfloat16* base =
                WhT2 + (size_t)((j0base >> 5) + ts) * 4096 + lane * 8;
            #pragma unroll
            for (int half = 0; half < 2; ++half) {
                bf16x8 bc[4];
                #pragma unroll
                for (int f = 0; f < 4; ++f)
                    bc[f] = *(const bf16x8*)(base + (half * 4 + f) * 512);
                #pragma unroll
                for (int f = 0; f < 4; ++f)
                    acc[half * 4 + f] =
                        __builtin_amdgcn_mfma_f32_16x16x32_bf16(afrag, bc[f], acc[half * 4 + f], 0, 0, 0);
            }
        }
    }
    {
        float v = dsum;
        v += __shfl_xor(v, 16);
        v += __shfl_xor(v, 32);
        if (lane < 16) atomicAdd(&denom[row0 + w * 16 + lane], v);
    }
    #pragma unroll
    for (int f = 0; f < 8; ++f)
        #pragma unroll
        for (int i = 0; i < 4; ++i) {
            int rr = row0 + w * 16 + kq * 4 + i;
            int cc = f * 16 + r16;
            atomicAdd(&y[(size_t)rr * H_DIM + cc], acc[f][i]);
        }
}

// alpha_ij = ex_ij / denom_i ; reads 8MB bitmask (or adj fallback), writes 268MB nt
__global__ __launch_bounds__(256) void k_B(const unsigned long long* __restrict__ bmask,
                                           const float* __restrict__ adj,
                                           const float* __restrict__ s,
                                           const float* __restrict__ denom,
                                           const unsigned int* __restrict__ smaxp,
                                           float* __restrict__ alpha,
                                           int use_mask) {
    const int NSTEP = N_NODES / 256;
    const int w = threadIdx.x >> 6, lane = threadIdx.x & 63;
    const int row = blockIdx.x * 4 + w;
    const float smax = mono2f(*smaxp);
    const float si = s[row];
    const float mi = lrelu(si + smax);
    const float d = denom[row];
    const float rd = d > 0.f ? 1.f / d : 0.f;
    float* arow = alpha + (size_t)row * N_NODES;
    if (use_mask) {
        const unsigned long long* mrow = bmask + (size_t)row * NTW;
        #pragma unroll 4
        for (int t = 0; t < NSTEP; ++t) {
            int col = t * 256 + lane * 4;
            unsigned long long mb = mrow[t * 4 + (lane >> 4)];
            int sh = (lane & 15) * 4;
            f32x4 sj = *(const f32x4*)&s[col];
            f32x4 o;
            o[0] = ((mb >> (sh + 0)) & 1ull) ? __expf(lrelu(si + sj[0]) - mi) * rd : 0.f;
            o[1] = ((mb >> (sh + 1)) & 1ull) ? __expf(lrelu(si + sj[1]) - mi) * rd : 0.f;
            o[2] = ((mb >> (sh + 2)) & 1ull) ? __expf(lrelu(si + sj[2]) - mi) * rd : 0.f;
            o[3] = ((mb >> (sh + 3)) & 1ull) ? __expf(lrelu(si + sj[3]) - mi) * rd : 0.f;
            __builtin_nontemporal_store(o, (f32x4*)&arow[col]);
        }
    } else {
        const float* adjrow = adj + (size_t)row * N_NODES;
        #pragma unroll 4
        for (int t = 0; t < NSTEP; ++t) {
            int col = t * 256 + lane * 4;
            f32x4 a4 = __builtin_nontemporal_load((const f32x4*)&adjrow[col]);
            f32x4 sj = *(const f32x4*)&s[col];
            f32x4 o;
            o[0] = (a4[0] != 0.f) ? __expf(lrelu(si + sj[0]) - mi) * rd : 0.f;
            o[1] = (a4[1] != 0.f) ? __expf(lrelu(si + sj[1]) - mi) * rd : 0.f;
            o[2] = (a4[2] != 0.f) ? __expf(lrelu(si + sj[2]) - mi) * rd : 0.f;
            o[3] = (a4[3] != 0.f) ? __expf(lrelu(si + sj[3]) - mi) * rd : 0.f;
            __builtin_nontemporal_store(o, (f32x4*)&arow[col]);
        }
    }
}

// z = sigmoid(y/denom)
__global__ __launch_bounds__(256) void k_z(const float* __restrict__ y,
                                           const float* __restrict__ denom,
                                           float* __restrict__ z) {
    int i = blockIdx.x * 256 + threadIdx.x;
    int row = i >> 7;
    float d = denom[row];
    float rd = d > 0.f ? 1.f / d : 0.f;
    float v = y[i] * rd;
    z[i] = 1.f / (1.f + __expf(-v));
}

extern "C" void kernel_launch(void* const* d_in, const int* in_sizes, int n_in,
                              void* d_out, int out_size, void* d_ws, size_t ws_size,
                              hipStream_t stream) {
    const float* h   = (const float*)d_in[0];
    const float* adj = (const float*)d_in[1];
    const float* Ww  = (const float*)d_in[2];
    const float* Wb  = (const float*)d_in[3];
    const float* a   = (const float*)d_in[4];

    float* z     = (float*)d_out;
    float* alpha = z + (size_t)N_NODES * H_DIM;

    char* ws = (char*)d_ws;
    float* y     = (float*)ws;  ws += sizeof(float) * (size_t)N_NODES * H_DIM;   // 4MB (zeroed)
    float* denom = (float*)ws;  ws += sizeof(float) * N_NODES;                   // 32KB (zeroed)
    unsigned int* smax = (unsigned int*)ws;  ws += 256;                          // (zeroed)
    size_t zero_bytes = (size_t)(ws - (char*)d_ws);
    float* Wh    = (float*)ws;  ws += sizeof(float) * (size_t)N_NODES * H_DIM;   // 4MB
    __hip_bfloat16* WhT2 = (__hip_bfloat16*)ws;
    ws += sizeof(__hip_bfloat16) * (size_t)N_NODES * H_DIM;                      // 2MB
    float* s     = (float*)ws;  ws += sizeof(float) * N_NODES;                   // 32KB
    unsigned long long* bmask = (unsigned long long*)ws;
    size_t base_need  = (size_t)(ws - (char*)d_ws);
    size_t mask_bytes = (size_t)N_NODES * NTW * sizeof(unsigned long long);      // 8MB
    int use_mask = (ws_size >= base_need + mask_bytes) ? 1 : 0;

    int n16 = (int)(zero_bytes / 16);
    hipLaunchKernelGGL(k_zero, dim3((n16 + 255) / 256), dim3(256), 0, stream,
                       (f32x4*)d_ws, n16);
    if (use_mask)
        hipLaunchKernelGGL(k_mask, dim3(N_NODES / 4), dim3(256), 0, stream, adj, bmask);
    hipLaunchKernelGGL(k_wh, dim3(N_NODES / 32), dim3(256), 0, stream, h, Ww, Wb, Wh, WhT2);
    hipLaunchKernelGGL(k_s,  dim3(N_NODES / 4),  dim3(256), 0, stream, Wh, a, s, smax);
    if (use_mask)
        hipLaunchKernelGGL(k_A, dim3(N_NODES / BMR, NKB), dim3(256), 0, stream,
                           bmask, WhT2, s, smax, denom, y);
    else
        hipLaunchKernelGGL(k_A_fb, dim3(N_NODES / BMR, NKB), dim3(256), 0, stream,
                           adj, WhT2, s, smax, denom, y);
    hipLaunchKernelGGL(k_B,  dim3(N_NODES / 4),  dim3(256), 0, stream,
                       bmask, adj, s, denom, smax, alpha, use_mask);
    hipLaunchKernelGGL(k_z,  dim3((N_NODES * H_DIM) / 256), dim3(256), 0, stream,
                       y, denom, z);
}

// Round 13
// 244.546 us; speedup vs baseline: 1.2825x; 1.0320x over previous
//
#include <hip/hip_runtime.h>
#include <hip/hip_bf16.h>
#include <math.h>

#define N_NODES 8192
#define IN_DIM  512
#define H_DIM   128
#define KC      1024              // K-chunk per k-block in k_A
#define NKB     (N_NODES / KC)    // 8
#define BMRA    128               // adj rows per k_A block (4 waves x 32 rows)
#define NTW     (N_NODES / 64)    // bitmask u64 words per row (128)

typedef __attribute__((ext_vector_type(8))) short bf16x8;
typedef __attribute__((ext_vector_type(4))) float f32x4;

__device__ __forceinline__ float lrelu(float x) { return fmaxf(x, 0.2f * x); }

__device__ __forceinline__ unsigned int f2mono(float x) {
    unsigned int b = __float_as_uint(x);
    return (b & 0x80000000u) ? ~b : (b | 0x80000000u);
}
__device__ __forceinline__ float mono2f(unsigned int u) {
    unsigned int b = (u & 0x80000000u) ? (u ^ 0x80000000u) : ~u;
    return __uint_as_float(b);
}

__device__ __forceinline__ short f2bf(float x) {
    union { __hip_bfloat16 h; short s; } cv;
    cv.h = __float2bfloat16(x);
    return cv.s;
}

// Zero-fill (hipMemsetAsync's fillBufferAligned ran at 27 GB/s in round 10)
__global__ __launch_bounds__(256) void k_zero(f32x4* __restrict__ p, int n16) {
    int i = blockIdx.x * 256 + threadIdx.x;
    if (i < n16) {
        f32x4 zv = {0.f, 0.f, 0.f, 0.f};
        __builtin_nontemporal_store(zv, p + i);
    }
}

// Wh = h @ W_w^T + W_b (f32) ; also WhT2 = bf16 FRAGMENT-SWIZZLED transpose.
//   element (node j, hcol c): ts=j>>5, kq=(j>>3)&3, e=j&7, f=c>>4, r16=c&15
//   WhT2[ ((ts*8+f)*64 + kq*16+r16)*8 + e ]
__global__ __launch_bounds__(256) void k_wh(const float* __restrict__ h,
                                            const float* __restrict__ Ww,
                                            const float* __restrict__ Wb,
                                            float* __restrict__ Wh,
                                            __hip_bfloat16* __restrict__ WhT2) {
    const int BM = 32, BK = 64;
    __shared__ float hT[BK][BM + 4];
    __shared__ float wT[BK][H_DIM + 4];
    const int tid = threadIdx.x;
    const int w = tid >> 6, lane = tid & 63;
    const int trm = tid >> 5, tcm = tid & 31;
    const int row0 = blockIdx.x * BM;

    float acc[4][4] = {};
    for (int k0 = 0; k0 < IN_DIM; k0 += BK) {
        __syncthreads();
        #pragma unroll
        for (int p = 0; p < 8; ++p) {
            int r = 4 * p + w;
            hT[lane][r] = h[(size_t)(row0 + r) * IN_DIM + k0 + lane];
        }
        #pragma unroll
        for (int p = 0; p < 32; ++p) {
            int c = 4 * p + w;
            wT[lane][c] = Ww[(size_t)c * IN_DIM + k0 + lane];
        }
        __syncthreads();
        #pragma unroll 8
        for (int kk = 0; kk < BK; ++kk) {
            f32x4 a4 = *(const f32x4*)&hT[kk][4 * trm];
            f32x4 b4 = *(const f32x4*)&wT[kk][4 * tcm];
            #pragma unroll
            for (int i = 0; i < 4; ++i)
                #pragma unroll
                for (int j = 0; j < 4; ++j)
                    acc[i][j] = fmaf(a4[i], b4[j], acc[i][j]);
        }
    }
    f32x4 wb4 = *(const f32x4*)&Wb[4 * tcm];
    #pragma unroll
    for (int i = 0; i < 4; ++i) {
        int row = row0 + 4 * trm + i;          // node j
        f32x4 v;
        #pragma unroll
        for (int jj = 0; jj < 4; ++jj) v[jj] = acc[i][jj] + wb4[jj];
        *(f32x4*)&Wh[(size_t)row * H_DIM + 4 * tcm] = v;
        int ts = row >> 5, kq = (row >> 3) & 3, e = row & 7;
        #pragma unroll
        for (int jj = 0; jj < 4; ++jj) {
            int c = 4 * tcm + jj;
            int f = c >> 4, r16 = c & 15;
            WhT2[((size_t)(ts * 8 + f) * 64 + kq * 16 + r16) * 8 + e] =
                __float2bfloat16(v[jj]);
        }
    }
}

// s_i = Wh_i . a ; global max(s) via mapped atomicMax
__global__ __launch_bounds__(256) void k_s(const float* __restrict__ Wh,
                                           const float* __restrict__ a,
                                           float* __restrict__ s,
                                           unsigned int* __restrict__ smax) {
    const int w = threadIdx.x >> 6, lane = threadIdx.x & 63;
    const int row = blockIdx.x * 4 + w;
    float2 av = *(const float2*)&a[lane * 2];
    float2 wh = *(const float2*)&Wh[(size_t)row * H_DIM + lane * 2];
    float v = wh.x * av.x + wh.y * av.y;
    #pragma unroll
    for (int off = 32; off > 0; off >>= 1) v += __shfl_down(v, off);
    __shared__ float bmax[4];
    if (lane == 0) { s[row] = v; bmax[w] = v; }
    __syncthreads();
    if (threadIdx.x == 0) {
        float m = fmaxf(fmaxf(bmax[0], bmax[1]), fmaxf(bmax[2], bmax[3]));
        atomicMax(smax, f2mono(m));
    }
}

// Streaming compress: bmask[row] bit j = (adj[row][j] != 0).
__global__ __launch_bounds__(256) void k_mask(const float* __restrict__ adj,
                                              unsigned long long* __restrict__ bm) {
    const int lane = threadIdx.x & 63;
    const int row  = blockIdx.x * 4 + (threadIdx.x >> 6);
    const float* arow = adj + (size_t)row * N_NODES;
    unsigned long long* mrow = bm + (size_t)row * NTW;
    #pragma unroll 4
    for (int c = 0; c < N_NODES / 256; ++c) {      // 32 chunks of 256 cols
        f32x4 a4 = __builtin_nontemporal_load((const f32x4*)(arow + c * 256 + lane * 4));
        unsigned long long v = 0ull;
        v |= (a4[0] != 0.f) ? 1ull : 0ull;
        v |= (a4[1] != 0.f) ? 2ull : 0ull;
        v |= (a4[2] != 0.f) ? 4ull : 0ull;
        v |= (a4[3] != 0.f) ? 8ull : 0ull;
        v <<= (4 * (lane & 15));
        v |= __shfl_xor(v, 1);
        v |= __shfl_xor(v, 2);
        v |= __shfl_xor(v, 4);
        v |= __shfl_xor(v, 8);
        if ((lane & 15) == 0)
            mrow[c * 4 + (lane >> 4)] = v;
    }
}

// MFMA pass, round-13: each wave owns 32 rows (two A-fragments) x all 128 H
// cols -> the 8 bc loads per substep feed 16 MFMAs (halves WhT2 re-read
// traffic, the round-12 profile's residual). y goes to per-k-chunk partial
// buffers with plain stores (kills the 8.4M atomicAdd RMWs); k_z2 reduces.
__global__ __launch_bounds__(256) void k_A(const unsigned long long* __restrict__ bm,
                                           const __hip_bfloat16* __restrict__ WhT2,
                                           const float* __restrict__ s,
                                           const unsigned int* __restrict__ smaxp,
                                           float* __restrict__ denom,
                                           float* __restrict__ y,
                                           float* __restrict__ ypart,
                                           int use_part) {
    const int lane = threadIdx.x & 63;
    const int w    = threadIdx.x >> 6;   // wave = row-group of 32
    const int r16  = lane & 15;
    const int kq   = lane >> 4;          // k-quarter: k = kq*8 + e
    const int rowB = blockIdx.x * BMRA + w * 32;
    const int j0   = blockIdx.y * KC;
    const int rowA0 = rowB + r16;
    const int rowA1 = rowB + 16 + r16;

    const float smax = mono2f(*smaxp);
    const float si0 = s[rowA0], si1 = s[rowA1];
    const float mi0 = lrelu(si0 + smax), mi1 = lrelu(si1 + smax);

    f32x4 acc0[8], acc1[8];
    {
        f32x4 zv = {0.f, 0.f, 0.f, 0.f};
        #pragma unroll
        for (int f = 0; f < 8; ++f) { acc0[f] = zv; acc1[f] = zv; }
    }
    float dsum0 = 0.f, dsum1 = 0.f;

    const float* sp = s + j0 + kq * 8;
    const unsigned long long* mrow0 = bm + (size_t)rowA0 * NTW + (j0 >> 6);
    const unsigned long long* mrow1 = bm + (size_t)rowA1 * NTW + (j0 >> 6);

    for (int bs = 0; bs < KC / 64; ++bs) {         // 16 mask words per row
        unsigned long long m64a = mrow0[bs];
        unsigned long long m64b = mrow1[bs];
        #pragma unroll
        for (int sub = 0; sub < 2; ++sub) {
            const int ts = bs * 2 + sub;           // 32-col step in [0, KC/32)
            unsigned int bits0 = (unsigned int)(m64a >> (sub * 32 + kq * 8)) & 0xffu;
            unsigned int bits1 = (unsigned int)(m64b >> (sub * 32 + kq * 8)) & 0xffu;

            f32x4 sc0 = *(const f32x4*)(sp + ts * 32);
            f32x4 sc1 = *(const f32x4*)(sp + ts * 32 + 4);
            float sv[8] = {sc0[0], sc0[1], sc0[2], sc0[3], sc1[0], sc1[1], sc1[2], sc1[3]};
            bf16x8 af0, af1;
            #pragma unroll
            for (int e = 0; e < 8; ++e) {
                float ex0 = ((bits0 >> e) & 1u) ? __expf(lrelu(si0 + sv[e]) - mi0) : 0.f;
                float ex1 = ((bits1 >> e) & 1u) ? __expf(lrelu(si1 + sv[e]) - mi1) : 0.f;
                dsum0 += ex0; dsum1 += ex1;
                af0[e] = f2bf(ex0);
                af1[e] = f2bf(ex1);
            }
            const __hip_bfloat16* base =
                WhT2 + (size_t)((j0 >> 5) + ts) * 4096 + lane * 8;
            #pragma unroll
            for (int half = 0; half < 2; ++half) {
                bf16x8 bc[4];
                #pragma unroll
                for (int f = 0; f < 4; ++f)
                    bc[f] = *(const bf16x8*)(base + (half * 4 + f) * 512);
                #pragma unroll
                for (int f = 0; f < 4; ++f) {
                    acc0[half * 4 + f] =
                        __builtin_amdgcn_mfma_f32_16x16x32_bf16(af0, bc[f], acc0[half * 4 + f], 0, 0, 0);
                    acc1[half * 4 + f] =
                        __builtin_amdgcn_mfma_f32_16x16x32_bf16(af1, bc[f], acc1[half * 4 + f], 0, 0, 0);
                }
            }
        }
    }

    // denom partials: reduce over kq lanes (same r16)
    {
        float v0 = dsum0, v1 = dsum1;
        v0 += __shfl_xor(v0, 16); v0 += __shfl_xor(v0, 32);
        v1 += __shfl_xor(v1, 16); v1 += __shfl_xor(v1, 32);
        if (lane < 16) {
            atomicAdd(&denom[rowB + lane], v0);
            atomicAdd(&denom[rowB + 16 + lane], v1);
        }
    }
    // y out: D layout row = kq*4 + i (within 16-row group), col = f*16 + r16
    if (use_part) {
        float* yp = ypart + (size_t)blockIdx.y * N_NODES * H_DIM;
        #pragma unroll
        for (int f = 0; f < 8; ++f)
            #pragma unroll
            for (int i = 0; i < 4; ++i) {
                int cc = f * 16 + r16;
                yp[(size_t)(rowB + kq * 4 + i) * H_DIM + cc] = acc0[f][i];
                yp[(size_t)(rowB + 16 + kq * 4 + i) * H_DIM + cc] = acc1[f][i];
            }
    } else {
        #pragma unroll
        for (int f = 0; f < 8; ++f)
            #pragma unroll
            for (int i = 0; i < 4; ++i) {
                int cc = f * 16 + r16;
                atomicAdd(&y[(size_t)(rowB + kq * 4 + i) * H_DIM + cc], acc0[f][i]);
                atomicAdd(&y[(size_t)(rowB + 16 + kq * 4 + i) * H_DIM + cc], acc1[f][i]);
            }
    }
}

// Fallback (ws too small for bmask): staged adj-direct (round-9 structure),
// 16 rows/wave, atomics into y. Grid (N/64, NKB).
__global__ __launch_bounds__(256) void k_A_fb(const float* __restrict__ adj,
                                              const __hip_bfloat16* __restrict__ WhT2,
                                              const float* __restrict__ s,
                                              const unsigned int* __restrict__ smaxp,
                                              float* __restrict__ denom,
                                              float* __restrict__ y) {
    __shared__ unsigned char msk[64 * 64];
    const int tid  = threadIdx.x;
    const int lane = tid & 63;
    const int w    = tid >> 6;
    const int r16  = lane & 15;
    const int kq   = lane >> 4;
    const int row0 = blockIdx.x * 64;
    const int j0base = blockIdx.y * KC;
    const int rowA = row0 + w * 16 + r16;

    const float smax = mono2f(*smaxp);
    const float si = s[rowA];
    const float mi = lrelu(si + smax);

    f32x4 acc[8];
    {
        f32x4 zv = {0.f, 0.f, 0.f, 0.f};
        #pragma unroll
        for (int f = 0; f < 8; ++f) acc[f] = zv;
    }
    float dsum = 0.f;

    const float* sp = s + j0base + kq * 8;

    int sRow[4], sCol[4];
    #pragma unroll
    for (int p = 0; p < 4; ++p) {
        int seg = p * 256 + tid;
        sRow[p] = seg >> 4;
        sCol[p] = (seg & 15) * 4;
    }
    const int NBIG = KC / 64;
    f32x4 areg[4];
    #pragma unroll
    for (int p = 0; p < 4; ++p)
        areg[p] = __builtin_nontemporal_load(
            (const f32x4*)(adj + (size_t)(row0 + sRow[p]) * N_NODES + j0base + sCol[p]));

    for (int bs = 0; bs < NBIG; ++bs) {
        __syncthreads();
        #pragma unroll
        for (int p = 0; p < 4; ++p) {
            f32x4 a4 = areg[p];
            unsigned int mwd = 0u;
            mwd |= (a4[0] != 0.f) ? 0x00000001u : 0u;
            mwd |= (a4[1] != 0.f) ? 0x00000100u : 0u;
            mwd |= (a4[2] != 0.f) ? 0x00010000u : 0u;
            mwd |= (a4[3] != 0.f) ? 0x01000000u : 0u;
            int r = sRow[p], c = sCol[p];
            int slot = (c >> 3) ^ (r & 7);
            *(unsigned int*)&msk[r * 64 + (slot << 3) + (c & 7)] = mwd;
        }
        __syncthreads();
        if (bs + 1 < NBIG) {
            const int j1 = j0base + (bs + 1) * 64;
            #pragma unroll
            for (int p = 0; p < 4; ++p)
                areg[p] = __builtin_nontemporal_load(
                    (const f32x4*)(adj + (size_t)(row0 + sRow[p]) * N_NODES + j1 + sCol[p]));
        }
        #pragma unroll
        for (int sub = 0; sub < 2; ++sub) {
            const int ts = bs * 2 + sub;
            const int rT = w * 16 + r16;
            const int slotR = (sub * 4 + kq) ^ (r16 & 7);
            unsigned long long m8 = *(const unsigned long long*)&msk[rT * 64 + (slotR << 3)];
            unsigned int bits = (unsigned int)((m8 * 0x0102040810204080ull) >> 56) & 0xffu;

            f32x4 sc0 = *(const f32x4*)(sp + ts * 32);
            f32x4 sc1 = *(const f32x4*)(sp + ts * 32 + 4);
            float sv[8] = {sc0[0], sc0[1], sc0[2], sc0[3], sc1[0], sc1[1], sc1[2], sc1[3]};
            bf16x8 afrag;
            #pragma unroll
            for (int e = 0; e < 8; ++e) {
                bool nb = (bits >> e) & 1u;
                float ex = nb ? __expf(lrelu(si + sv[e]) - mi) : 0.f;
                dsum += ex;
                afrag[e] = f2bf(ex);
            }
            const __hip_bfloat16* base =
                WhT2 + (size_t)((j0base >> 5) + ts) * 4096 + lane * 8;
            #pragma unroll
            for (int half = 0; half < 2; ++half) {
                bf16x8 bc[4];
                #pragma unroll
                for (int f = 0; f < 4; ++f)
                    bc[f] = *(const bf16x8*)(base + (half * 4 + f) * 512);
                #pragma unroll
                for (int f = 0; f < 4; ++f)
                    acc[half * 4 + f] =
                        __builtin_amdgcn_mfma_f32_16x16x32_bf16(afrag, bc[f], acc[half * 4 + f], 0, 0, 0);
            }
        }
    }
    {
        float v = dsum;
        v += __shfl_xor(v, 16);
        v += __shfl_xor(v, 32);
        if (lane < 16) atomicAdd(&denom[row0 + w * 16 + lane], v);
    }
    #pragma unroll
    for (int f = 0; f < 8; ++f)
        #pragma unroll
        for (int i = 0; i < 4; ++i) {
            int rr = row0 + w * 16 + kq * 4 + i;
            int cc = f * 16 + r16;
            atomicAdd(&y[(size_t)rr * H_DIM + cc], acc[f][i]);
        }
}

// alpha_ij = ex_ij / denom_i ; reads 8MB bitmask (or adj fallback), writes 268MB nt
__global__ __launch_bounds__(256) void k_B(const unsigned long long* __restrict__ bmask,
                                           const float* __restrict__ adj,
                                           const float* __restrict__ s,
                                           const float* __restrict__ denom,
                                           const unsigned int* __restrict__ smaxp,
                                           float* __restrict__ alpha,
                                           int use_mask) {
    const int NSTEP = N_NODES / 256;
    const int w = threadIdx.x >> 6, lane = threadIdx.x & 63;
    const int row = blockIdx.x * 4 + w;
    const float smax = mono2f(*smaxp);
    const float si = s[row];
    const float mi = lrelu(si + smax);
    const float d = denom[row];
    const float rd = d > 0.f ? 1.f / d : 0.f;
    float* arow = alpha + (size_t)row * N_NODES;
    if (use_mask) {
        const unsigned long long* mrow = bmask + (size_t)row * NTW;
        #pragma unroll 4
        for (int t = 0; t < NSTEP; ++t) {
            int col = t * 256 + lane * 4;
            unsigned long long mb = mrow[t * 4 + (lane >> 4)];
            int sh = (lane & 15) * 4;
            f32x4 sj = *(const f32x4*)&s[col];
            f32x4 o;
            o[0] = ((mb >> (sh + 0)) & 1ull) ? __expf(lrelu(si + sj[0]) - mi) * rd : 0.f;
            o[1] = ((mb >> (sh + 1)) & 1ull) ? __expf(lrelu(si + sj[1]) - mi) * rd : 0.f;
            o[2] = ((mb >> (sh + 2)) & 1ull) ? __expf(lrelu(si + sj[2]) - mi) * rd : 0.f;
            o[3] = ((mb >> (sh + 3)) & 1ull) ? __expf(lrelu(si + sj[3]) - mi) * rd : 0.f;
            __builtin_nontemporal_store(o, (f32x4*)&arow[col]);
        }
    } else {
        const float* adjrow = adj + (size_t)row * N_NODES;
        #pragma unroll 4
        for (int t = 0; t < NSTEP; ++t) {
            int col = t * 256 + lane * 4;
            f32x4 a4 = __builtin_nontemporal_load((const f32x4*)&adjrow[col]);
            f32x4 sj = *(const f32x4*)&s[col];
            f32x4 o;
            o[0] = (a4[0] != 0.f) ? __expf(lrelu(si + sj[0]) - mi) * rd : 0.f;
            o[1] = (a4[1] != 0.f) ? __expf(lrelu(si + sj[1]) - mi) * rd : 0.f;
            o[2] = (a4[2] != 0.f) ? __expf(lrelu(si + sj[2]) - mi) * rd : 0.f;
            o[3] = (a4[3] != 0.f) ? __expf(lrelu(si + sj[3]) - mi) * rd : 0.f;
            __builtin_nontemporal_store(o, (f32x4*)&arow[col]);
        }
    }
}

// z = sigmoid(y/denom) -- atomic-path variant
__global__ __launch_bounds__(256) void k_z(const float* __restrict__ y,
                                           const float* __restrict__ denom,
                                           float* __restrict__ z) {
    int i = blockIdx.x * 256 + threadIdx.x;
    int row = i >> 7;
    float d = denom[row];
    float rd = d > 0.f ? 1.f / d : 0.f;
    float v = y[i] * rd;
    z[i] = 1.f / (1.f + __expf(-v));
}

// z = sigmoid(sum_p ypart[p]/denom) -- partial-buffer variant
__global__ __launch_bounds__(256) void k_z2(const float* __restrict__ ypart,
                                            const float* __restrict__ denom,
                                            float* __restrict__ z) {
    int i = blockIdx.x * 256 + threadIdx.x;
    int row = i >> 7;
    float d = denom[row];
    float rd = d > 0.f ? 1.f / d : 0.f;
    float v = 0.f;
    #pragma unroll
    for (int p = 0; p < NKB; ++p)
        v += ypart[(size_t)p * N_NODES * H_DIM + i];
    v *= rd;
    z[i] = 1.f / (1.f + __expf(-v));
}

extern "C" void kernel_launch(void* const* d_in, const int* in_sizes, int n_in,
                              void* d_out, int out_size, void* d_ws, size_t ws_size,
                              hipStream_t stream) {
    const float* h   = (const float*)d_in[0];
    const float* adj = (const float*)d_in[1];
    const float* Ww  = (const float*)d_in[2];
    const float* Wb  = (const float*)d_in[3];
    const float* a   = (const float*)d_in[4];

    float* z     = (float*)d_out;
    float* alpha = z + (size_t)N_NODES * H_DIM;

    char* ws = (char*)d_ws;
    float* y     = (float*)ws;  ws += sizeof(float) * (size_t)N_NODES * H_DIM;   // 4MB (zeroed)
    float* denom = (float*)ws;  ws += sizeof(float) * N_NODES;                   // 32KB (zeroed)
    unsigned int* smax = (unsigned int*)ws;  ws += 256;                          // (zeroed)
    size_t zero_bytes = (size_t)(ws - (char*)d_ws);
    float* Wh    = (float*)ws;  ws += sizeof(float) * (size_t)N_NODES * H_DIM;   // 4MB
    __hip_bfloat16* WhT2 = (__hip_bfloat16*)ws;
    ws += sizeof(__hip_bfloat16) * (size_t)N_NODES * H_DIM;                      // 2MB
    float* s     = (float*)ws;  ws += sizeof(float) * N_NODES;                   // 32KB
    unsigned long long* bmask = (unsigned long long*)ws;
    ws += (size_t)N_NODES * NTW * sizeof(unsigned long long);                    // 8MB
    size_t mask_need = (size_t)(ws - (char*)d_ws);
    float* ypart = (float*)ws;
    ws += (size_t)NKB * N_NODES * H_DIM * sizeof(float);                         // 32MB
    size_t part_need = (size_t)(ws - (char*)d_ws);
    int use_mask = (ws_size >= mask_need) ? 1 : 0;
    int use_part = (use_mask && ws_size >= part_need) ? 1 : 0;

    int n16 = (int)(zero_bytes / 16);
    hipLaunchKernelGGL(k_zero, dim3((n16 + 255) / 256), dim3(256), 0, stream,
                       (f32x4*)d_ws, n16);
    if (use_mask)
        hipLaunchKernelGGL(k_mask, dim3(N_NODES / 4), dim3(256), 0, stream, adj, bmask);
    hipLaunchKernelGGL(k_wh, dim3(N_NODES / 32), dim3(256), 0, stream, h, Ww, Wb, Wh, WhT2);
    hipLaunchKernelGGL(k_s,  dim3(N_NODES / 4),  dim3(256), 0, stream, Wh, a, s, smax);
    if (use_mask)
        hipLaunchKernelGGL(k_A, dim3(N_NODES / BMRA, NKB), dim3(256), 0, stream,
                           bmask, WhT2, s, smax, denom, y, ypart, use_part);
    else
        hipLaunchKernelGGL(k_A_fb, dim3(N_NODES / 64, NKB), dim3(256), 0, stream,
                           adj, WhT2, s, smax, denom, y);
    hipLaunchKernelGGL(k_B,  dim3(N_NODES / 4),  dim3(256), 0, stream,
                       bmask, adj, s, denom, smax, alpha, use_mask);
    if (use_part)
        hipLaunchKernelGGL(k_z2, dim3((N_NODES * H_DIM) / 256), dim3(256), 0, stream,
                           ypart, denom, z);
    else
        hipLaunchKernelGGL(k_z, dim3((N_NODES * H_DIM) / 256), dim3(256), 0, stream,
                           y, denom, z);
}

// Round 14
// 234.734 us; speedup vs baseline: 1.3361x; 1.0418x over previous
//
#include <hip/hip_runtime.h>
#include <hip/hip_bf16.h>
#include <math.h>

#define N_NODES 8192
#define IN_DIM  512
#define H_DIM   128
#define KC      1024              // K-chunk per k-block in k_A
#define NKB     (N_NODES / KC)    // 8
#define BMRA    128               // adj rows per k_A block (4 waves x 32 rows)
#define NTW     (N_NODES / 64)    // bitmask u64 words per row (128)
#define NB_WH   (N_NODES / 32)    // 256 wh tiles
#define NB_MASK (N_NODES / 4)     // 2048 mask blocks
#define NB_B    (N_NODES / 4)     // 2048 k_B blocks
#define NB_Z    ((N_NODES * H_DIM) / 256)  // 4096 z blocks

typedef __attribute__((ext_vector_type(8))) short bf16x8;
typedef __attribute__((ext_vector_type(4))) float f32x4;

__device__ __forceinline__ float lrelu(float x) { return fmaxf(x, 0.2f * x); }

__device__ __forceinline__ unsigned int f2mono(float x) {
    unsigned int b = __float_as_uint(x);
    return (b & 0x80000000u) ? ~b : (b | 0x80000000u);
}
__device__ __forceinline__ float mono2f(unsigned int u) {
    unsigned int b = (u & 0x80000000u) ? (u ^ 0x80000000u) : ~u;
    return __uint_as_float(b);
}

__device__ __forceinline__ short f2bf(float x) {
    union { __hip_bfloat16 h; short s; } cv;
    cv.h = __float2bfloat16(x);
    return cv.s;
}

// ---------------- fused front: k_wh || k_mask || k_zero ----------------
// All three are mutually independent (disjoint outputs; inputs read-only),
// so one grid-split dispatch overlaps the compute-bound GEMM with the
// 268MB adj->bitmask stream and the workspace zeroing.
__global__ __launch_bounds__(256) void k_front(const float* __restrict__ h,
                                               const float* __restrict__ Ww,
                                               const float* __restrict__ Wb,
                                               float* __restrict__ Wh,
                                               __hip_bfloat16* __restrict__ WhT2,
                                               const float* __restrict__ adj,
                                               unsigned long long* __restrict__ bm,
                                               f32x4* __restrict__ zp, int n16) {
    __shared__ float hT[64][32 + 4];
    __shared__ float wT[64][H_DIM + 4];
    const int tid = threadIdx.x;
    const int bx = blockIdx.x;

    if (bx < NB_WH) {
        // ---- Wh = h @ W_w^T + W_b ; WhT2 = fragment-swizzled bf16 ----
        const int w = tid >> 6, lane = tid & 63;
        const int trm = tid >> 5, tcm = tid & 31;
        const int row0 = bx * 32;

        float acc[4][4] = {};
        for (int k0 = 0; k0 < IN_DIM; k0 += 64) {
            __syncthreads();
            #pragma unroll
            for (int p = 0; p < 8; ++p) {
                int r = 4 * p + w;
                hT[lane][r] = h[(size_t)(row0 + r) * IN_DIM + k0 + lane];
            }
            #pragma unroll
            for (int p = 0; p < 32; ++p) {
                int c = 4 * p + w;
                wT[lane][c] = Ww[(size_t)c * IN_DIM + k0 + lane];
            }
            __syncthreads();
            #pragma unroll 8
            for (int kk = 0; kk < 64; ++kk) {
                f32x4 a4 = *(const f32x4*)&hT[kk][4 * trm];
                f32x4 b4 = *(const f32x4*)&wT[kk][4 * tcm];
                #pragma unroll
                for (int i = 0; i < 4; ++i)
                    #pragma unroll
                    for (int j = 0; j < 4; ++j)
                        acc[i][j] = fmaf(a4[i], b4[j], acc[i][j]);
            }
        }
        f32x4 wb4 = *(const f32x4*)&Wb[4 * tcm];
        #pragma unroll
        for (int i = 0; i < 4; ++i) {
            int row = row0 + 4 * trm + i;          // node j
            f32x4 v;
            #pragma unroll
            for (int jj = 0; jj < 4; ++jj) v[jj] = acc[i][jj] + wb4[jj];
            *(f32x4*)&Wh[(size_t)row * H_DIM + 4 * tcm] = v;
            int ts = row >> 5, kq = (row >> 3) & 3, e = row & 7;
            #pragma unroll
            for (int jj = 0; jj < 4; ++jj) {
                int c = 4 * tcm + jj;
                int f = c >> 4, r16 = c & 15;
                WhT2[((size_t)(ts * 8 + f) * 64 + kq * 16 + r16) * 8 + e] =
                    __float2bfloat16(v[jj]);
            }
        }
    } else if (bx < NB_WH + NB_MASK) {
        // ---- bmask[row] bit j = (adj[row][j] != 0) ----
        const int lane = tid & 63;
        const int row = (bx - NB_WH) * 4 + (tid >> 6);
        const float* arow = adj + (size_t)row * N_NODES;
        unsigned long long* mrow = bm + (size_t)row * NTW;
        #pragma unroll 4
        for (int c = 0; c < N_NODES / 256; ++c) {
            f32x4 a4 = __builtin_nontemporal_load((const f32x4*)(arow + c * 256 + lane * 4));
            unsigned long long v = 0ull;
            v |= (a4[0] != 0.f) ? 1ull : 0ull;
            v |= (a4[1] != 0.f) ? 2ull : 0ull;
            v |= (a4[2] != 0.f) ? 4ull : 0ull;
            v |= (a4[3] != 0.f) ? 8ull : 0ull;
            v <<= (4 * (lane & 15));
            v |= __shfl_xor(v, 1);
            v |= __shfl_xor(v, 2);
            v |= __shfl_xor(v, 4);
            v |= __shfl_xor(v, 8);
            if ((lane & 15) == 0)
                mrow[c * 4 + (lane >> 4)] = v;
        }
    } else {
        // ---- zero y/denom/smax (consumed only by LATER kernels) ----
        int i = (bx - NB_WH - NB_MASK) * 256 + tid;
        if (i < n16) {
            f32x4 zv = {0.f, 0.f, 0.f, 0.f};
            __builtin_nontemporal_store(zv, zp + i);
        }
    }
}

// standalone zero (fallback path)
__global__ __launch_bounds__(256) void k_zero(f32x4* __restrict__ p, int n16) {
    int i = blockIdx.x * 256 + threadIdx.x;
    if (i < n16) {
        f32x4 zv = {0.f, 0.f, 0.f, 0.f};
        __builtin_nontemporal_store(zv, p + i);
    }
}

// standalone k_wh (fallback path)
__global__ __launch_bounds__(256) void k_wh(const float* __restrict__ h,
                                            const float* __restrict__ Ww,
                                            const float* __restrict__ Wb,
                                            float* __restrict__ Wh,
                                            __hip_bfloat16* __restrict__ WhT2) {
    __shared__ float hT[64][32 + 4];
    __shared__ float wT[64][H_DIM + 4];
    const int tid = threadIdx.x;
    const int w = tid >> 6, lane = tid & 63;
    const int trm = tid >> 5, tcm = tid & 31;
    const int row0 = blockIdx.x * 32;

    float acc[4][4] = {};
    for (int k0 = 0; k0 < IN_DIM; k0 += 64) {
        __syncthreads();
        #pragma unroll
        for (int p = 0; p < 8; ++p) {
            int r = 4 * p + w;
            hT[lane][r] = h[(size_t)(row0 + r) * IN_DIM + k0 + lane];
        }
        #pragma unroll
        for (int p = 0; p < 32; ++p) {
            int c = 4 * p + w;
            wT[lane][c] = Ww[(size_t)c * IN_DIM + k0 + lane];
        }
        __syncthreads();
        #pragma unroll 8
        for (int kk = 0; kk < 64; ++kk) {
            f32x4 a4 = *(const f32x4*)&hT[kk][4 * trm];
            f32x4 b4 = *(const f32x4*)&wT[kk][4 * tcm];
            #pragma unroll
            for (int i = 0; i < 4; ++i)
                #pragma unroll
                for (int j = 0; j < 4; ++j)
                    acc[i][j] = fmaf(a4[i], b4[j], acc[i][j]);
        }
    }
    f32x4 wb4 = *(const f32x4*)&Wb[4 * tcm];
    #pragma unroll
    for (int i = 0; i < 4; ++i) {
        int row = row0 + 4 * trm + i;
        f32x4 v;
        #pragma unroll
        for (int jj = 0; jj < 4; ++jj) v[jj] = acc[i][jj] + wb4[jj];
        *(f32x4*)&Wh[(size_t)row * H_DIM + 4 * tcm] = v;
        int ts = row >> 5, kq = (row >> 3) & 3, e = row & 7;
        #pragma unroll
        for (int jj = 0; jj < 4; ++jj) {
            int c = 4 * tcm + jj;
            int f = c >> 4, r16 = c & 15;
            WhT2[((size_t)(ts * 8 + f) * 64 + kq * 16 + r16) * 8 + e] =
                __float2bfloat16(v[jj]);
        }
    }
}

// s_i = Wh_i . a ; global max(s) via mapped atomicMax
__global__ __launch_bounds__(256) void k_s(const float* __restrict__ Wh,
                                           const float* __restrict__ a,
                                           float* __restrict__ s,
                                           unsigned int* __restrict__ smax) {
    const int w = threadIdx.x >> 6, lane = threadIdx.x & 63;
    const int row = blockIdx.x * 4 + w;
    float2 av = *(const float2*)&a[lane * 2];
    float2 wh = *(const float2*)&Wh[(size_t)row * H_DIM + lane * 2];
    float v = wh.x * av.x + wh.y * av.y;
    #pragma unroll
    for (int off = 32; off > 0; off >>= 1) v += __shfl_down(v, off);
    __shared__ float bmax[4];
    if (lane == 0) { s[row] = v; bmax[w] = v; }
    __syncthreads();
    if (threadIdx.x == 0) {
        float m = fmaxf(fmaxf(bmax[0], bmax[1]), fmaxf(bmax[2], bmax[3]));
        atomicMax(smax, f2mono(m));
    }
}

// MFMA pass (round-13 structure): each wave owns 32 rows x all 128 H cols.
__global__ __launch_bounds__(256) void k_A(const unsigned long long* __restrict__ bm,
                                           const __hip_bfloat16* __restrict__ WhT2,
                                           const float* __restrict__ s,
                                           const unsigned int* __restrict__ smaxp,
                                           float* __restrict__ denom,
                                           float* __restrict__ y,
                                           float* __restrict__ ypart,
                                           int use_part) {
    const int lane = threadIdx.x & 63;
    const int w    = threadIdx.x >> 6;
    const int r16  = lane & 15;
    const int kq   = lane >> 4;
    const int rowB = blockIdx.x * BMRA + w * 32;
    const int j0   = blockIdx.y * KC;
    const int rowA0 = rowB + r16;
    const int rowA1 = rowB + 16 + r16;

    const float smax = mono2f(*smaxp);
    const float si0 = s[rowA0], si1 = s[rowA1];
    const float mi0 = lrelu(si0 + smax), mi1 = lrelu(si1 + smax);

    f32x4 acc0[8], acc1[8];
    {
        f32x4 zv = {0.f, 0.f, 0.f, 0.f};
        #pragma unroll
        for (int f = 0; f < 8; ++f) { acc0[f] = zv; acc1[f] = zv; }
    }
    float dsum0 = 0.f, dsum1 = 0.f;

    const float* sp = s + j0 + kq * 8;
    const unsigned long long* mrow0 = bm + (size_t)rowA0 * NTW + (j0 >> 6);
    const unsigned long long* mrow1 = bm + (size_t)rowA1 * NTW + (j0 >> 6);

    for (int bs = 0; bs < KC / 64; ++bs) {
        unsigned long long m64a = mrow0[bs];
        unsigned long long m64b = mrow1[bs];
        #pragma unroll
        for (int sub = 0; sub < 2; ++sub) {
            const int ts = bs * 2 + sub;
            unsigned int bits0 = (unsigned int)(m64a >> (sub * 32 + kq * 8)) & 0xffu;
            unsigned int bits1 = (unsigned int)(m64b >> (sub * 32 + kq * 8)) & 0xffu;

            f32x4 sc0 = *(const f32x4*)(sp + ts * 32);
            f32x4 sc1 = *(const f32x4*)(sp + ts * 32 + 4);
            float sv[8] = {sc0[0], sc0[1], sc0[2], sc0[3], sc1[0], sc1[1], sc1[2], sc1[3]};
            bf16x8 af0, af1;
            #pragma unroll
            for (int e = 0; e < 8; ++e) {
                float ex0 = ((bits0 >> e) & 1u) ? __expf(lrelu(si0 + sv[e]) - mi0) : 0.f;
                float ex1 = ((bits1 >> e) & 1u) ? __expf(lrelu(si1 + sv[e]) - mi1) : 0.f;
                dsum0 += ex0; dsum1 += ex1;
                af0[e] = f2bf(ex0);
                af1[e] = f2bf(ex1);
            }
            const __hip_bfloat16* base =
                WhT2 + (size_t)((j0 >> 5) + ts) * 4096 + lane * 8;
            #pragma unroll
            for (int half = 0; half < 2; ++half) {
                bf16x8 bc[4];
                #pragma unroll
                for (int f = 0; f < 4; ++f)
                    bc[f] = *(const bf16x8*)(base + (half * 4 + f) * 512);
                #pragma unroll
                for (int f = 0; f < 4; ++f) {
                    acc0[half * 4 + f] =
                        __builtin_amdgcn_mfma_f32_16x16x32_bf16(af0, bc[f], acc0[half * 4 + f], 0, 0, 0);
                    acc1[half * 4 + f] =
                        __builtin_amdgcn_mfma_f32_16x16x32_bf16(af1, bc[f], acc1[half * 4 + f], 0, 0, 0);
                }
            }
        }
    }

    {
        float v0 = dsum0, v1 = dsum1;
        v0 += __shfl_xor(v0, 16); v0 += __shfl_xor(v0, 32);
        v1 += __shfl_xor(v1, 16); v1 += __shfl_xor(v1, 32);
        if (lane < 16) {
            atomicAdd(&denom[rowB + lane], v0);
            atomicAdd(&denom[rowB + 16 + lane], v1);
        }
    }
    if (use_part) {
        float* yp = ypart + (size_t)blockIdx.y * N_NODES * H_DIM;
        #pragma unroll
        for (int f = 0; f < 8; ++f)
            #pragma unroll
            for (int i = 0; i < 4; ++i) {
                int cc = f * 16 + r16;
                yp[(size_t)(rowB + kq * 4 + i) * H_DIM + cc] = acc0[f][i];
                yp[(size_t)(rowB + 16 + kq * 4 + i) * H_DIM + cc] = acc1[f][i];
            }
    } else {
        #pragma unroll
        for (int f = 0; f < 8; ++f)
            #pragma unroll
            for (int i = 0; i < 4; ++i) {
                int cc = f * 16 + r16;
                atomicAdd(&y[(size_t)(rowB + kq * 4 + i) * H_DIM + cc], acc0[f][i]);
                atomicAdd(&y[(size_t)(rowB + 16 + kq * 4 + i) * H_DIM + cc], acc1[f][i]);
            }
    }
}

// Fallback (ws too small for bmask): staged adj-direct.
__global__ __launch_bounds__(256) void k_A_fb(const float* __restrict__ adj,
                                              const __hip_bfloat16* __restrict__ WhT2,
                                              const float* __restrict__ s,
                                              const unsigned int* __restrict__ smaxp,
                                              float* __restrict__ denom,
                                              float* __restrict__ y) {
    __shared__ unsigned char msk[64 * 64];
    const int tid  = threadIdx.x;
    const int lane = tid & 63;
    const int w    = tid >> 6;
    const int r16  = lane & 15;
    const int kq   = lane >> 4;
    const int row0 = blockIdx.x * 64;
    const int j0base = blockIdx.y * KC;
    const int rowA = row0 + w * 16 + r16;

    const float smax = mono2f(*smaxp);
    const float si = s[rowA];
    const float mi = lrelu(si + smax);

    f32x4 acc[8];
    {
        f32x4 zv = {0.f, 0.f, 0.f, 0.f};
        #pragma unroll
        for (int f = 0; f < 8; ++f) acc[f] = zv;
    }
    float dsum = 0.f;

    const float* sp = s + j0base + kq * 8;

    int sRow[4], sCol[4];
    #pragma unroll
    for (int p = 0; p < 4; ++p) {
        int seg = p * 256 + tid;
        sRow[p] = seg >> 4;
        sCol[p] = (seg & 15) * 4;
    }
    const int NBIG = KC / 64;
    f32x4 areg[4];
    #pragma unroll
    for (int p = 0; p < 4; ++p)
        areg[p] = __builtin_nontemporal_load(
            (const f32x4*)(adj + (size_t)(row0 + sRow[p]) * N_NODES + j0base + sCol[p]));

    for (int bs = 0; bs < NBIG; ++bs) {
        __syncthreads();
        #pragma unroll
        for (int p = 0; p < 4; ++p) {
            f32x4 a4 = areg[p];
            unsigned int mwd = 0u;
            mwd |= (a4[0] != 0.f) ? 0x00000001u : 0u;
            mwd |= (a4[1] != 0.f) ? 0x00000100u : 0u;
            mwd |= (a4[2] != 0.f) ? 0x00010000u : 0u;
            mwd |= (a4[3] != 0.f) ? 0x01000000u : 0u;
            int r = sRow[p], c = sCol[p];
            int slot = (c >> 3) ^ (r & 7);
            *(unsigned int*)&msk[r * 64 + (slot << 3) + (c & 7)] = mwd;
        }
        __syncthreads();
        if (bs + 1 < NBIG) {
            const int j1 = j0base + (bs + 1) * 64;
            #pragma unroll
            for (int p = 0; p < 4; ++p)
                areg[p] = __builtin_nontemporal_load(
                    (const f32x4*)(adj + (size_t)(row0 + sRow[p]) * N_NODES + j1 + sCol[p]));
        }
        #pragma unroll
        for (int sub = 0; sub < 2; ++sub) {
            const int ts = bs * 2 + sub;
            const int rT = w * 16 + r16;
            const int slotR = (sub * 4 + kq) ^ (r16 & 7);
            unsigned long long m8 = *(const unsigned long long*)&msk[rT * 64 + (slotR << 3)];
            unsigned int bits = (unsigned int)((m8 * 0x0102040810204080ull) >> 56) & 0xffu;

            f32x4 sc0 = *(const f32x4*)(sp + ts * 32);
            f32x4 sc1 = *(const f32x4*)(sp + ts * 32 + 4);
            float sv[8] = {sc0[0], sc0[1], sc0[2], sc0[3], sc1[0], sc1[1], sc1[2], sc1[3]};
            bf16x8 afrag;
            #pragma unroll
            for (int e = 0; e < 8; ++e) {
                bool nb = (bits >> e) & 1u;
                float ex = nb ? __expf(lrelu(si + sv[e]) - mi) : 0.f;
                dsum += ex;
                afrag[e] = f2bf(ex);
            }
            const __hip_bfloat16* base =
                WhT2 + (size_t)((j0base >> 5) + ts) * 4096 + lane * 8;
            #pragma unroll
            for (int half = 0; half < 2; ++half) {
                bf16x8 bc[4];
                #pragma unroll
                for (int f = 0; f < 4; ++f)
                    bc[f] = *(const bf16x8*)(base + (half * 4 + f) * 512);
                #pragma unroll
                for (int f = 0; f < 4; ++f)
                    acc[half * 4 + f] =
                        __builtin_amdgcn_mfma_f32_16x16x32_bf16(afrag, bc[f], acc[half * 4 + f], 0, 0, 0);
            }
        }
    }
    {
        float v = dsum;
        v += __shfl_xor(v, 16);
        v += __shfl_xor(v, 32);
        if (lane < 16) atomicAdd(&denom[row0 + w * 16 + lane], v);
    }
    #pragma unroll
    for (int f = 0; f < 8; ++f)
        #pragma unroll
        for (int i = 0; i < 4; ++i) {
            int rr = row0 + w * 16 + kq * 4 + i;
            int cc = f * 16 + r16;
            atomicAdd(&y[(size_t)rr * H_DIM + cc], acc[f][i]);
        }
}

// ---------------- fused back: k_B || k_z ----------------
// Both depend only on k_A's outputs (denom, ypart/y) + earlier buffers;
// grid-split so the 268MB alpha write stream hides the z reduction.
__global__ __launch_bounds__(256) void k_back(const unsigned long long* __restrict__ bmask,
                                              const float* __restrict__ adj,
                                              const float* __restrict__ s,
                                              const float* __restrict__ denom,
                                              const unsigned int* __restrict__ smaxp,
                                              float* __restrict__ alpha,
                                              const float* __restrict__ ypart,
                                              const float* __restrict__ y,
                                              float* __restrict__ z,
                                              int use_mask, int use_part) {
    const int tid = threadIdx.x;
    const int bx = blockIdx.x;
    if (bx < NB_B) {
        const int NSTEP = N_NODES / 256;
        const int w = tid >> 6, lane = tid & 63;
        const int row = bx * 4 + w;
        const float smax = mono2f(*smaxp);
        const float si = s[row];
        const float mi = lrelu(si + smax);
        const float d = denom[row];
        const float rd = d > 0.f ? 1.f / d : 0.f;
        float* arow = alpha + (size_t)row * N_NODES;
        if (use_mask) {
            const unsigned long long* mrow = bmask + (size_t)row * NTW;
            #pragma unroll 4
            for (int t = 0; t < NSTEP; ++t) {
                int col = t * 256 + lane * 4;
                unsigned long long mb = mrow[t * 4 + (lane >> 4)];
                int sh = (lane & 15) * 4;
                f32x4 sj = *(const f32x4*)&s[col];
                f32x4 o;
                o[0] = ((mb >> (sh + 0)) & 1ull) ? __expf(lrelu(si + sj[0]) - mi) * rd : 0.f;
                o[1] = ((mb >> (sh + 1)) & 1ull) ? __expf(lrelu(si + sj[1]) - mi) * rd : 0.f;
                o[2] = ((mb >> (sh + 2)) & 1ull) ? __expf(lrelu(si + sj[2]) - mi) * rd : 0.f;
                o[3] = ((mb >> (sh + 3)) & 1ull) ? __expf(lrelu(si + sj[3]) - mi) * rd : 0.f;
                __builtin_nontemporal_store(o, (f32x4*)&arow[col]);
            }
        } else {
            const float* adjrow = adj + (size_t)row * N_NODES;
            #pragma unroll 4
            for (int t = 0; t < NSTEP; ++t) {
                int col = t * 256 + lane * 4;
                f32x4 a4 = __builtin_nontemporal_load((const f32x4*)&adjrow[col]);
                f32x4 sj = *(const f32x4*)&s[col];
                f32x4 o;
                o[0] = (a4[0] != 0.f) ? __expf(lrelu(si + sj[0]) - mi) * rd : 0.f;
                o[1] = (a4[1] != 0.f) ? __expf(lrelu(si + sj[1]) - mi) * rd : 0.f;
                o[2] = (a4[2] != 0.f) ? __expf(lrelu(si + sj[2]) - mi) * rd : 0.f;
                o[3] = (a4[3] != 0.f) ? __expf(lrelu(si + sj[3]) - mi) * rd : 0.f;
                __builtin_nontemporal_store(o, (f32x4*)&arow[col]);
            }
        }
    } else {
        int i = (bx - NB_B) * 256 + tid;
        int row = i >> 7;
        float d = denom[row];
        float rd = d > 0.f ? 1.f / d : 0.f;
        float v = 0.f;
        if (use_part) {
            #pragma unroll
            for (int p = 0; p < NKB; ++p)
                v += ypart[(size_t)p * N_NODES * H_DIM + i];
        } else {
            v = y[i];
        }
        v *= rd;
        z[i] = 1.f / (1.f + __expf(-v));
    }
}

extern "C" void kernel_launch(void* const* d_in, const int* in_sizes, int n_in,
                              void* d_out, int out_size, void* d_ws, size_t ws_size,
                              hipStream_t stream) {
    const float* h   = (const float*)d_in[0];
    const float* adj = (const float*)d_in[1];
    const float* Ww  = (const float*)d_in[2];
    const float* Wb  = (const float*)d_in[3];
    const float* a   = (const float*)d_in[4];

    float* z     = (float*)d_out;
    float* alpha = z + (size_t)N_NODES * H_DIM;

    char* ws = (char*)d_ws;
    float* y     = (float*)ws;  ws += sizeof(float) * (size_t)N_NODES * H_DIM;   // 4MB (zeroed)
    float* denom = (float*)ws;  ws += sizeof(float) * N_NODES;                   // 32KB (zeroed)
    unsigned int* smax = (unsigned int*)ws;  ws += 256;                          // (zeroed)
    size_t zero_bytes = (size_t)(ws - (char*)d_ws);
    float* Wh    = (float*)ws;  ws += sizeof(float) * (size_t)N_NODES * H_DIM;   // 4MB
    __hip_bfloat16* WhT2 = (__hip_bfloat16*)ws;
    ws += sizeof(__hip_bfloat16) * (size_t)N_NODES * H_DIM;                      // 2MB
    float* s     = (float*)ws;  ws += sizeof(float) * N_NODES;                   // 32KB
    unsigned long long* bmask = (unsigned long long*)ws;
    ws += (size_t)N_NODES * NTW * sizeof(unsigned long long);                    // 8MB
    size_t mask_need = (size_t)(ws - (char*)d_ws);
    float* ypart = (float*)ws;
    ws += (size_t)NKB * N_NODES * H_DIM * sizeof(float);                         // 32MB
    size_t part_need = (size_t)(ws - (char*)d_ws);
    int use_mask = (ws_size >= mask_need) ? 1 : 0;
    int use_part = (use_mask && ws_size >= part_need) ? 1 : 0;

    int n16 = (int)(zero_bytes / 16);
    int nbz = (n16 + 255) / 256;

    if (use_mask) {
        // fused front: wh (256 blocks, first so they start early) || mask || zero
        hipLaunchKernelGGL(k_front, dim3(NB_WH + NB_MASK + nbz), dim3(256), 0, stream,
                           h, Ww, Wb, Wh, WhT2, adj, bmask, (f32x4*)d_ws, n16);
        hipLaunchKernelGGL(k_s, dim3(N_NODES / 4), dim3(256), 0, stream, Wh, a, s, smax);
        hipLaunchKernelGGL(k_A, dim3(N_NODES / BMRA, NKB), dim3(256), 0, stream,
                           bmask, WhT2, s, smax, denom, y, ypart, use_part);
        hipLaunchKernelGGL(k_back, dim3(NB_B + NB_Z), dim3(256), 0, stream,
                           bmask, adj, s, denom, smax, alpha, ypart, y, z,
                           use_mask, use_part);
    } else {
        hipLaunchKernelGGL(k_zero, dim3(nbz), dim3(256), 0, stream, (f32x4*)d_ws, n16);
        hipLaunchKernelGGL(k_wh, dim3(NB_WH), dim3(256), 0, stream, h, Ww, Wb, Wh, WhT2);
        hipLaunchKernelGGL(k_s, dim3(N_NODES / 4), dim3(256), 0, stream, Wh, a, s, smax);
        hipLaunchKernelGGL(k_A_fb, dim3(N_NODES / 64, NKB), dim3(256), 0, stream,
                           adj, WhT2, s, smax, denom, y);
        hipLaunchKernelGGL(k_back, dim3(NB_B + NB_Z), dim3(256), 0, stream,
                           bmask, adj, s, denom, smax, alpha, ypart, y, z,
                           use_mask, use_part);
    }
}

// Round 16
// 231.727 us; speedup vs baseline: 1.3535x; 1.0130x over previous
//
#include <hip/hip_runtime.h>
#include <hip/hip_bf16.h>
#include <math.h>

#define N_NODES 8192
#define IN_DIM  512
#define H_DIM   128
#define KC      1024              // K-chunk per k_A block
#define NKB     (N_NODES / KC)    // 8
#define BMRA    128               // adj rows per k_A block (4 waves x 32 rows)
#define NTW     (N_NODES / 64)    // bitmask u64 words per row (128)
#define NB_WH   (N_NODES / 32)    // 256 wh tiles
#define NB_MASK (N_NODES / 4)     // 2048 mask/denom blocks
#define NB_A    ((N_NODES / BMRA) * NKB)   // 512 k_A blocks
#define NB_B    (N_NODES / 4)     // 2048 k_B blocks

typedef __attribute__((ext_vector_type(8))) short bf16x8;
typedef __attribute__((ext_vector_type(4))) float f32x4;

__device__ __forceinline__ float lrelu(float x) { return fmaxf(x, 0.2f * x); }

__device__ __forceinline__ unsigned int f2mono(float x) {
    unsigned int b = __float_as_uint(x);
    return (b & 0x80000000u) ? ~b : (b | 0x80000000u);
}
__device__ __forceinline__ float mono2f(unsigned int u) {
    unsigned int b = (u & 0x80000000u) ? (u ^ 0x80000000u) : ~u;
    return __uint_as_float(b);
}

__device__ __forceinline__ short f2bf(float x) {
    union { __hip_bfloat16 h; short s; } cv;
    cv.h = __float2bfloat16(x);
    return cv.s;
}

// w_a = W_w^T @ a (512), b_a = W_b . a, smax init. One block.
// Enables s = h @ w_a + b_a WITHOUT Wh -> s/smax ready before the big passes,
// which lets denom be computed inside the adj stream (k_front2).
__global__ __launch_bounds__(256) void k_wa(const float* __restrict__ Ww,
                                            const float* __restrict__ Wb,
                                            const float* __restrict__ a,
                                            float* __restrict__ wa,
                                            float* __restrict__ ba,
                                            unsigned int* __restrict__ smax) {
    const int t = threadIdx.x;
    #pragma unroll
    for (int kk = 0; kk < 2; ++kk) {
        int k = t + kk * 256;
        float sum = 0.f;
        #pragma unroll 8
        for (int c = 0; c < H_DIM; ++c)
            sum += Ww[(size_t)c * IN_DIM + k] * a[c];
        wa[k] = sum;
    }
    __shared__ float red[256];
    red[t] = (t < H_DIM) ? Wb[t] * a[t] : 0.f;
    __syncthreads();
    for (int off = 128; off > 0; off >>= 1) {
        if (t < off) red[t] += red[t + off];
        __syncthreads();
    }
    if (t == 0) { ba[0] = red[0]; *smax = 0u; }
}

// s_i = h_i . w_a + b_a ; smax via mapped atomicMax. 4 rows/block (wave each).
__global__ __launch_bounds__(256) void k_s0(const float* __restrict__ h,
                                            const float* __restrict__ wa,
                                            const float* __restrict__ ba,
                                            float* __restrict__ s,
                                            unsigned int* __restrict__ smax) {
    const int w = threadIdx.x >> 6, lane = threadIdx.x & 63;
    const int row = blockIdx.x * 4 + w;
    const float* hp = h + (size_t)row * IN_DIM + lane * 8;
    f32x4 h0 = *(const f32x4*)(hp);
    f32x4 h1 = *(const f32x4*)(hp + 4);
    f32x4 w0 = *(const f32x4*)(wa + lane * 8);
    f32x4 w1 = *(const f32x4*)(wa + lane * 8 + 4);
    float v = h0[0]*w0[0] + h0[1]*w0[1] + h0[2]*w0[2] + h0[3]*w0[3]
            + h1[0]*w1[0] + h1[1]*w1[1] + h1[2]*w1[2] + h1[3]*w1[3];
    #pragma unroll
    for (int off = 32; off > 0; off >>= 1) v += __shfl_down(v, off);
    __shared__ float bmax[4];
    if (lane == 0) { float sv = v + ba[0]; s[row] = sv; bmax[w] = sv; }
    __syncthreads();
    if (threadIdx.x == 0) {
        float m = fmaxf(fmaxf(bmax[0], bmax[1]), fmaxf(bmax[2], bmax[3]));
        atomicMax(smax, f2mono(m));
    }
}

// ---------------- fused front2: k_wh || (mask + denom) ----------------
// wh tiles: WhT2 fragment-swizzled bf16 (f32 Wh dropped -- nothing consumes it).
// mask waves: stream one full adj row each -> bitmask word writes + f32
// exp-sum -> denom[row] written directly (no atomics; s/smax ready via k_s0).
__global__ __launch_bounds__(256) void k_front2(const float* __restrict__ h,
                                                const float* __restrict__ Ww,
                                                const float* __restrict__ Wb,
                                                __hip_bfloat16* __restrict__ WhT2,
                                                const float* __restrict__ adj,
                                                unsigned long long* __restrict__ bm,
                                                const float* __restrict__ s,
                                                const unsigned int* __restrict__ smaxp,
                                                float* __restrict__ denom) {
    __shared__ float hT[64][32 + 4];
    __shared__ float wT[64][H_DIM + 4];
    const int tid = threadIdx.x;
    const int bx = blockIdx.x;

    if (bx < NB_WH) {
        const int w = tid >> 6, lane = tid & 63;
        const int trm = tid >> 5, tcm = tid & 31;
        const int row0 = bx * 32;

        float acc[4][4] = {};
        for (int k0 = 0; k0 < IN_DIM; k0 += 64) {
            __syncthreads();
            #pragma unroll
            for (int p = 0; p < 8; ++p) {
                int r = 4 * p + w;
                hT[lane][r] = h[(size_t)(row0 + r) * IN_DIM + k0 + lane];
            }
            #pragma unroll
            for (int p = 0; p < 32; ++p) {
                int c = 4 * p + w;
                wT[lane][c] = Ww[(size_t)c * IN_DIM + k0 + lane];
            }
            __syncthreads();
            #pragma unroll 8
            for (int kk = 0; kk < 64; ++kk) {
                f32x4 a4 = *(const f32x4*)&hT[kk][4 * trm];
                f32x4 b4 = *(const f32x4*)&wT[kk][4 * tcm];
                #pragma unroll
                for (int i = 0; i < 4; ++i)
                    #pragma unroll
                    for (int j = 0; j < 4; ++j)
                        acc[i][j] = fmaf(a4[i], b4[j], acc[i][j]);
            }
        }
        f32x4 wb4 = *(const f32x4*)&Wb[4 * tcm];
        #pragma unroll
        for (int i = 0; i < 4; ++i) {
            int row = row0 + 4 * trm + i;          // node j
            int ts = row >> 5, kq = (row >> 3) & 3, e = row & 7;
            #pragma unroll
            for (int jj = 0; jj < 4; ++jj) {
                int c = 4 * tcm + jj;
                int f = c >> 4, r16 = c & 15;
                WhT2[((size_t)(ts * 8 + f) * 64 + kq * 16 + r16) * 8 + e] =
                    __float2bfloat16(acc[i][jj] + wb4[jj]);
            }
        }
    } else {
        const int lane = tid & 63;
        const int row = (bx - NB_WH) * 4 + (tid >> 6);
        const float* arow = adj + (size_t)row * N_NODES;
        unsigned long long* mrow = bm + (size_t)row * NTW;
        const float smax = mono2f(*smaxp);
        const float si = s[row];
        const float mi = lrelu(si + smax);
        float dsum = 0.f;
        #pragma unroll 4
        for (int c = 0; c < N_NODES / 256; ++c) {
            int col = c * 256 + lane * 4;
            f32x4 a4 = __builtin_nontemporal_load((const f32x4*)(arow + col));
            f32x4 sj = *(const f32x4*)&s[col];
            unsigned long long v = 0ull;
            #pragma unroll
            for (int q = 0; q < 4; ++q) {
                bool nb = (a4[q] != 0.f);
                v |= nb ? (1ull << q) : 0ull;
                dsum += nb ? __expf(lrelu(si + sj[q]) - mi) : 0.f;
            }
            v <<= (4 * (lane & 15));
            v |= __shfl_xor(v, 1);
            v |= __shfl_xor(v, 2);
            v |= __shfl_xor(v, 4);
            v |= __shfl_xor(v, 8);
            if ((lane & 15) == 0)
                mrow[c * 4 + (lane >> 4)] = v;
        }
        #pragma unroll
        for (int off = 32; off > 0; off >>= 1) dsum += __shfl_down(dsum, off);
        if (lane == 0) denom[row] = dsum;
    }
}

// ---------------- fused mid: k_A (ypart) || k_B (alpha) ----------------
// Independent given front2's outputs (bitmask, denom, WhT2, s, smax):
// the MFMA y-pass hides inside the 268MB alpha write stream.
__global__ __launch_bounds__(256) void k_mid(const unsigned long long* __restrict__ bm,
                                             const __hip_bfloat16* __restrict__ WhT2,
                                             const float* __restrict__ s,
                                             const unsigned int* __restrict__ smaxp,
                                             const float* __restrict__ denom,
                                             float* __restrict__ ypart,
                                             float* __restrict__ alpha) {
    const int tid = threadIdx.x;
    const int bx = blockIdx.x;
    const float smax = mono2f(*smaxp);

    if (bx < NB_A) {
        // ---- k_A: each wave owns 32 rows x all 128 H cols ----
        const int lane = tid & 63;
        const int w    = tid >> 6;
        const int r16  = lane & 15;
        const int kq   = lane >> 4;
        const int xb   = bx & 63;
        const int yb   = bx >> 6;
        const int rowB = xb * BMRA + w * 32;
        const int j0   = yb * KC;
        const int rowA0 = rowB + r16;
        const int rowA1 = rowB + 16 + r16;

        const float si0 = s[rowA0], si1 = s[rowA1];
        const float mi0 = lrelu(si0 + smax), mi1 = lrelu(si1 + smax);

        f32x4 acc0[8], acc1[8];
        {
            f32x4 zv = {0.f, 0.f, 0.f, 0.f};
            #pragma unroll
            for (int f = 0; f < 8; ++f) { acc0[f] = zv; acc1[f] = zv; }
        }
        const float* sp = s + j0 + kq * 8;
        const unsigned long long* mrow0 = bm + (size_t)rowA0 * NTW + (j0 >> 6);
        const unsigned long long* mrow1 = bm + (size_t)rowA1 * NTW + (j0 >> 6);

        for (int bs = 0; bs < KC / 64; ++bs) {
            unsigned long long m64a = mrow0[bs];
            unsigned long long m64b = mrow1[bs];
            #pragma unroll
            for (int sub = 0; sub < 2; ++sub) {
                const int ts = bs * 2 + sub;
                unsigned int bits0 = (unsigned int)(m64a >> (sub * 32 + kq * 8)) & 0xffu;
                unsigned int bits1 = (unsigned int)(m64b >> (sub * 32 + kq * 8)) & 0xffu;

                f32x4 sc0 = *(const f32x4*)(sp + ts * 32);
                f32x4 sc1 = *(const f32x4*)(sp + ts * 32 + 4);
                float sv[8] = {sc0[0], sc0[1], sc0[2], sc0[3], sc1[0], sc1[1], sc1[2], sc1[3]};
                bf16x8 af0, af1;
                #pragma unroll
                for (int e = 0; e < 8; ++e) {
                    float ex0 = ((bits0 >> e) & 1u) ? __expf(lrelu(si0 + sv[e]) - mi0) : 0.f;
                    float ex1 = ((bits1 >> e) & 1u) ? __expf(lrelu(si1 + sv[e]) - mi1) : 0.f;
                    af0[e] = f2bf(ex0);
                    af1[e] = f2bf(ex1);
                }
                const __hip_bfloat16* base =
                    WhT2 + (size_t)((j0 >> 5) + ts) * 4096 + lane * 8;
                #pragma unroll
                for (int half = 0; half < 2; ++half) {
                    bf16x8 bc[4];
                    #pragma unroll
                    for (int f = 0; f < 4; ++f)
                        bc[f] = *(const bf16x8*)(base + (half * 4 + f) * 512);
                    #pragma unroll
                    for (int f = 0; f < 4; ++f) {
                        acc0[half * 4 + f] =
                            __builtin_amdgcn_mfma_f32_16x16x32_bf16(af0, bc[f], acc0[half * 4 + f], 0, 0, 0);
                        acc1[half * 4 + f] =
                            __builtin_amdgcn_mfma_f32_16x16x32_bf16(af1, bc[f], acc1[half * 4 + f], 0, 0, 0);
                    }
                }
            }
        }
        float* yp = ypart + (size_t)yb * N_NODES * H_DIM;
        #pragma unroll
        for (int f = 0; f < 8; ++f)
            #pragma unroll
            for (int i = 0; i < 4; ++i) {
                int cc = f * 16 + r16;
                yp[(size_t)(rowB + kq * 4 + i) * H_DIM + cc] = acc0[f][i];
                yp[(size_t)(rowB + 16 + kq * 4 + i) * H_DIM + cc] = acc1[f][i];
            }
    } else {
        // ---- k_B: alpha = ex/denom, 268MB nt write stream ----
        const int NSTEP = N_NODES / 256;
        const int w = tid >> 6, lane = tid & 63;
        const int row = (bx - NB_A) * 4 + w;
        const float si = s[row];
        const float mi = lrelu(si + smax);
        const float d = denom[row];
        const float rd = d > 0.f ? 1.f / d : 0.f;
        float* arow = alpha + (size_t)row * N_NODES;
        const unsigned long long* mrow = bm + (size_t)row * NTW;
        #pragma unroll 4
        for (int t = 0; t < NSTEP; ++t) {
            int col = t * 256 + lane * 4;
            unsigned long long mb = mrow[t * 4 + (lane >> 4)];
            int sh = (lane & 15) * 4;
            f32x4 sj = *(const f32x4*)&s[col];
            f32x4 o;
            o[0] = ((mb >> (sh + 0)) & 1ull) ? __expf(lrelu(si + sj[0]) - mi) * rd : 0.f;
            o[1] = ((mb >> (sh + 1)) & 1ull) ? __expf(lrelu(si + sj[1]) - mi) * rd : 0.f;
            o[2] = ((mb >> (sh + 2)) & 1ull) ? __expf(lrelu(si + sj[2]) - mi) * rd : 0.f;
            o[3] = ((mb >> (sh + 3)) & 1ull) ? __expf(lrelu(si + sj[3]) - mi) * rd : 0.f;
            __builtin_nontemporal_store(o, (f32x4*)&arow[col]);
        }
    }
}

// z = sigmoid(sum_p ypart[p]/denom)
__global__ __launch_bounds__(256) void k_z2(const float* __restrict__ ypart,
                                            const float* __restrict__ denom,
                                            float* __restrict__ z) {
    int i = blockIdx.x * 256 + threadIdx.x;
    int row = i >> 7;
    float d = denom[row];
    float rd = d > 0.f ? 1.f / d : 0.f;
    float v = 0.f;
    #pragma unroll
    for (int p = 0; p < NKB; ++p)
        v += ypart[(size_t)p * N_NODES * H_DIM + i];
    v *= rd;
    z[i] = 1.f / (1.f + __expf(-v));
}

// ---------------- fallback path (ws too small): serial, adj-direct ----------------
__global__ __launch_bounds__(256) void k_zero(f32x4* __restrict__ p, int n16) {
    int i = blockIdx.x * 256 + threadIdx.x;
    if (i < n16) {
        f32x4 zv = {0.f, 0.f, 0.f, 0.f};
        __builtin_nontemporal_store(zv, p + i);
    }
}

__global__ __launch_bounds__(256) void k_wh_fb(const float* __restrict__ h,
                                               const float* __restrict__ Ww,
                                               const float* __restrict__ Wb,
                                               __hip_bfloat16* __restrict__ WhT2) {
    __shared__ float hT[64][32 + 4];
    __shared__ float wT[64][H_DIM + 4];
    const int tid = threadIdx.x;
    const int w = tid >> 6, lane = tid & 63;
    const int trm = tid >> 5, tcm = tid & 31;
    const int row0 = blockIdx.x * 32;

    float acc[4][4] = {};
    for (int k0 = 0; k0 < IN_DIM; k0 += 64) {
        __syncthreads();
        #pragma unroll
        for (int p = 0; p < 8; ++p) {
            int r = 4 * p + w;
            hT[lane][r] = h[(size_t)(row0 + r) * IN_DIM + k0 + lane];
        }
        #pragma unroll
        for (int p = 0; p < 32; ++p) {
            int c = 4 * p + w;
            wT[lane][c] = Ww[(size_t)c * IN_DIM + k0 + lane];
        }
        __syncthreads();
        #pragma unroll 8
        for (int kk = 0; kk < 64; ++kk) {
            f32x4 a4 = *(const f32x4*)&hT[kk][4 * trm];
            f32x4 b4 = *(const f32x4*)&wT[kk][4 * tcm];
            #pragma unroll
            for (int i = 0; i < 4; ++i)
                #pragma unroll
                for (int j = 0; j < 4; ++j)
                    acc[i][j] = fmaf(a4[i], b4[j], acc[i][j]);
        }
    }
    f32x4 wb4 = *(const f32x4*)&Wb[4 * tcm];
    #pragma unroll
    for (int i = 0; i < 4; ++i) {
        int row = row0 + 4 * trm + i;
        int ts = row >> 5, kq = (row >> 3) & 3, e = row & 7;
        #pragma unroll
        for (int jj = 0; jj < 4; ++jj) {
            int c = 4 * tcm + jj;
            int f = c >> 4, r16 = c & 15;
            WhT2[((size_t)(ts * 8 + f) * 64 + kq * 16 + r16) * 8 + e] =
                __float2bfloat16(acc[i][jj] + wb4[jj]);
        }
    }
}

__global__ __launch_bounds__(256) void k_A_fb(const float* __restrict__ adj,
                                              const __hip_bfloat16* __restrict__ WhT2,
                                              const float* __restrict__ s,
                                              const unsigned int* __restrict__ smaxp,
                                              float* __restrict__ denom,
                                              float* __restrict__ y) {
    __shared__ unsigned char msk[64 * 64];
    const int tid  = threadIdx.x;
    const int lane = tid & 63;
    const int w    = tid >> 6;
    const int r16  = lane & 15;
    const int kq   = lane >> 4;
    const int row0 = blockIdx.x * 64;
    const int j0base = blockIdx.y * KC;
    const int rowA = row0 + w * 16 + r16;

    const float smax = mono2f(*smaxp);
    const float si = s[rowA];
    const float mi = lrelu(si + smax);

    f32x4 acc[8];
    {
        f32x4 zv = {0.f, 0.f, 0.f, 0.f};
        #pragma unroll
        for (int f = 0; f < 8; ++f) acc[f] = zv;
    }
    float dsum = 0.f;
    const float* sp = s + j0base + kq * 8;

    int sRow[4], sCol[4];
    #pragma unroll
    for (int p = 0; p < 4; ++p) {
        int seg = p * 256 + tid;
        sRow[p] = seg >> 4;
        sCol[p] = (seg & 15) * 4;
    }
    const int NBIG = KC / 64;
    f32x4 areg[4];
    #pragma unroll
    for (int p = 0; p < 4; ++p)
        areg[p] = __builtin_nontemporal_load(
            (const f32x4*)(adj + (size_t)(row0 + sRow[p]) * N_NODES + j0base + sCol[p]));

    for (int bs = 0; bs < NBIG; ++bs) {
        __syncthreads();
        #pragma unroll
        for (int p = 0; p < 4; ++p) {
            f32x4 a4 = areg[p];
            unsigned int mwd = 0u;
            mwd |= (a4[0] != 0.f) ? 0x00000001u : 0u;
            mwd |= (a4[1] != 0.f) ? 0x00000100u : 0u;
            mwd |= (a4[2] != 0.f) ? 0x00010000u : 0u;
            mwd |= (a4[3] != 0.f) ? 0x01000000u : 0u;
            int r = sRow[p], c = sCol[p];
            int slot = (c >> 3) ^ (r & 7);
            *(unsigned int*)&msk[r * 64 + (slot << 3) + (c & 7)] = mwd;
        }
        __syncthreads();
        if (bs + 1 < NBIG) {
            const int j1 = j0base + (bs + 1) * 64;
            #pragma unroll
            for (int p = 0; p < 4; ++p)
                areg[p] = __builtin_nontemporal_load(
                    (const f32x4*)(adj + (size_t)(row0 + sRow[p]) * N_NODES + j1 + sCol[p]));
        }
        #pragma unroll
        for (int sub = 0; sub < 2; ++sub) {
            const int ts = bs * 2 + sub;
            const int rT = w * 16 + r16;
            const int slotR = (sub * 4 + kq) ^ (r16 & 7);
            unsigned long long m8 = *(const unsigned long long*)&msk[rT * 64 + (slotR << 3)];
            unsigned int bits = (unsigned int)((m8 * 0x0102040810204080ull) >> 56) & 0xffu;

            f32x4 sc0 = *(const f32x4*)(sp + ts * 32);
            f32x4 sc1 = *(const f32x4*)(sp + ts * 32 + 4);
            float sv[8] = {sc0[0], sc0[1], sc0[2], sc0[3], sc1[0], sc1[1], sc1[2], sc1[3]};
            bf16x8 afrag;
            #pragma unroll
            for (int e = 0; e < 8; ++e) {
                bool nb = (bits >> e) & 1u;
                float ex = nb ? __expf(lrelu(si + sv[e]) - mi) : 0.f;
                dsum += ex;
                afrag[e] = f2bf(ex);
            }
            const __hip_bfloat16* base =
                WhT2 + (size_t)((j0base >> 5) + ts) * 4096 + lane * 8;
            #pragma unroll
            for (int half = 0; half < 2; ++half) {
                bf16x8 bc[4];
                #pragma unroll
                for (int f = 0; f < 4; ++f)
                    bc[f] = *(const bf16x8*)(base + (half * 4 + f) * 512);
                #pragma unroll
                for (int f = 0; f < 4; ++f)
                    acc[half * 4 + f] =
                        __builtin_amdgcn_mfma_f32_16x16x32_bf16(afrag, bc[f], acc[half * 4 + f], 0, 0, 0);
            }
        }
    }
    {
        float v = dsum;
        v += __shfl_xor(v, 16);
        v += __shfl_xor(v, 32);
        if (lane < 16) atomicAdd(&denom[row0 + w * 16 + lane], v);
    }
    #pragma unroll
    for (int f = 0; f < 8; ++f)
        #pragma unroll
        for (int i = 0; i < 4; ++i) {
            int rr = row0 + w * 16 + kq * 4 + i;
            int cc = f * 16 + r16;
            atomicAdd(&y[(size_t)rr * H_DIM + cc], acc[f][i]);
        }
}

__global__ __launch_bounds__(256) void k_B_fb(const float* __restrict__ adj,
                                              const float* __restrict__ s,
                                              const float* __restrict__ denom,
                                              const unsigned int* __restrict__ smaxp,
                                              float* __restrict__ alpha) {
    const int NSTEP = N_NODES / 256;
    const int w = threadIdx.x >> 6, lane = threadIdx.x & 63;
    const int row = blockIdx.x * 4 + w;
    const float smax = mono2f(*smaxp);
    const float si = s[row];
    const float mi = lrelu(si + smax);
    const float d = denom[row];
    const float rd = d > 0.f ? 1.f / d : 0.f;
    float* arow = alpha + (size_t)row * N_NODES;
    const float* adjrow = adj + (size_t)row * N_NODES;
    #pragma unroll 4
    for (int t = 0; t < NSTEP; ++t) {
        int col = t * 256 + lane * 4;
        f32x4 a4 = __builtin_nontemporal_load((const f32x4*)&adjrow[col]);
        f32x4 sj = *(const f32x4*)&s[col];
        f32x4 o;
        o[0] = (a4[0] != 0.f) ? __expf(lrelu(si + sj[0]) - mi) * rd : 0.f;
        o[1] = (a4[1] != 0.f) ? __expf(lrelu(si + sj[1]) - mi) * rd : 0.f;
        o[2] = (a4[2] != 0.f) ? __expf(lrelu(si + sj[2]) - mi) * rd : 0.f;
        o[3] = (a4[3] != 0.f) ? __expf(lrelu(si + sj[3]) - mi) * rd : 0.f;
        __builtin_nontemporal_store(o, (f32x4*)&arow[col]);
    }
}

__global__ __launch_bounds__(256) void k_z_fb(const float* __restrict__ y,
                                              const float* __restrict__ denom,
                                              float* __restrict__ z) {
    int i = blockIdx.x * 256 + threadIdx.x;
    int row = i >> 7;
    float d = denom[row];
    float rd = d > 0.f ? 1.f / d : 0.f;
    float v = y[i] * rd;
    z[i] = 1.f / (1.f + __expf(-v));
}

extern "C" void kernel_launch(void* const* d_in, const int* in_sizes, int n_in,
                              void* d_out, int out_size, void* d_ws, size_t ws_size,
                              hipStream_t stream) {
    const float* h   = (const float*)d_in[0];
    const float* adj = (const float*)d_in[1];
    const float* Ww  = (const float*)d_in[2];
    const float* Wb  = (const float*)d_in[3];
    const float* a   = (const float*)d_in[4];

    float* z     = (float*)d_out;
    float* alpha = z + (size_t)N_NODES * H_DIM;

    char* ws = (char*)d_ws;
    float* y     = (float*)ws;  ws += sizeof(float) * (size_t)N_NODES * H_DIM;   // 4MB (fallback only)
    float* denom = (float*)ws;  ws += sizeof(float) * N_NODES;                   // 32KB
    unsigned int* smax = (unsigned int*)ws;  ws += 256;
    size_t zero_bytes = (size_t)(ws - (char*)d_ws);
    float* wa    = (float*)ws;  ws += sizeof(float) * IN_DIM;                    // 2KB
    float* ba    = (float*)ws;  ws += 256;
    __hip_bfloat16* WhT2 = (__hip_bfloat16*)ws;
    ws += sizeof(__hip_bfloat16) * (size_t)N_NODES * H_DIM;                      // 2MB
    float* s     = (float*)ws;  ws += sizeof(float) * N_NODES;                   // 32KB
    unsigned long long* bmask = (unsigned long long*)ws;
    ws += (size_t)N_NODES * NTW * sizeof(unsigned long long);                    // 8MB
    float* ypart = (float*)ws;
    ws += (size_t)NKB * N_NODES * H_DIM * sizeof(float);                         // 32MB
    size_t full_need = (size_t)(ws - (char*)d_ws);
    int use_full = (ws_size >= full_need) ? 1 : 0;

    hipLaunchKernelGGL(k_wa, dim3(1), dim3(256), 0, stream, Ww, Wb, a, wa, ba, smax);
    hipLaunchKernelGGL(k_s0, dim3(N_NODES / 4), dim3(256), 0, stream, h, wa, ba, s, smax);

    if (use_full) {
        hipLaunchKernelGGL(k_front2, dim3(NB_WH + NB_MASK), dim3(256), 0, stream,
                           h, Ww, Wb, WhT2, adj, bmask, s, smax, denom);
        hipLaunchKernelGGL(k_mid, dim3(NB_A + NB_B), dim3(256), 0, stream,
                           bmask, WhT2, s, smax, denom, ypart, alpha);
        hipLaunchKernelGGL(k_z2, dim3((N_NODES * H_DIM) / 256), dim3(256), 0, stream,
                           ypart, denom, z);
    } else {
        int n16 = (int)(zero_bytes / 16);
        hipLaunchKernelGGL(k_zero, dim3((n16 + 255) / 256), dim3(256), 0, stream,
                           (f32x4*)d_ws, n16);
        hipLaunchKernelGGL(k_wh_fb, dim3(NB_WH), dim3(256), 0, stream, h, Ww, Wb, WhT2);
        hipLaunchKernelGGL(k_A_fb, dim3(N_NODES / 64, NKB), dim3(256), 0, stream,
                           adj, WhT2, s, smax, denom, y);
        hipLaunchKernelGGL(k_B_fb, dim3(N_NODES / 4), dim3(256), 0, stream,
                           adj, s, denom, smax, alpha);
        hipLaunchKernelGGL(k_z_fb, dim3((N_NODES * H_DIM) / 256), dim3(256), 0, stream,
                           y, denom, z);
    }
}